// Round 6
// baseline (288.383 us; speedup 1.0000x reference)
//
#include <hip/hip_runtime.h>
#include <hip/hip_bf16.h>

using bhalf = __hip_bfloat16;
typedef __bf16 bf16x8 __attribute__((ext_vector_type(8)));
typedef __bf16 bf16x2 __attribute__((ext_vector_type(2)));
typedef float f32x4 __attribute__((ext_vector_type(4)));

#define B_DIM 2
#define T_DIM 2048
#define D_DIM 1024
#define H_DIM 16
#define DH 64

struct bh8 { bhalf v[8]; };
struct bh4 { bhalf v[4]; };

__device__ __forceinline__ bf16x8 load_bf16x8(const bhalf* p) {
    return __builtin_bit_cast(bf16x8, *(const uint4*)p);
}
__device__ __forceinline__ bf16x8 zero_bf16x8() {
    uint4 z; z.x = 0; z.y = 0; z.z = 0; z.w = 0;
    return __builtin_bit_cast(bf16x8, z);
}
__device__ __forceinline__ void stage8_cvt(bhalf* dst, const float* src) {
    float4 a = *(const float4*)src;
    float4 b = *(const float4*)(src + 4);
    bh8 t;
    t.v[0] = __float2bfloat16(a.x); t.v[1] = __float2bfloat16(a.y);
    t.v[2] = __float2bfloat16(a.z); t.v[3] = __float2bfloat16(a.w);
    t.v[4] = __float2bfloat16(b.x); t.v[5] = __float2bfloat16(b.y);
    t.v[6] = __float2bfloat16(b.z); t.v[7] = __float2bfloat16(b.w);
    *(uint4*)dst = __builtin_bit_cast(uint4, t);
}

// async 16B global -> LDS (wave-uniform LDS base + lane*16)
#define GLD16(gp, lp) __builtin_amdgcn_global_load_lds( \
    (const __attribute__((address_space(1))) void*)(gp), \
    (__attribute__((address_space(3))) void*)(lp), 16, 0, 0)

// Segment sizes (elements)
#define SX  4194304
#define SW  3145728
#define SL  65536
#define SO  1048576
__global__ __launch_bounds__(256) void cvt_all(
    const float* __restrict__ x, const float* __restrict__ wqkv,
    const float* __restrict__ w1w, const float* __restrict__ w2w,
    const float* __restrict__ w1r, const float* __restrict__ w2r,
    const float* __restrict__ wout,
    bhalf* __restrict__ xbf, bhalf* __restrict__ wcat, bhalf* __restrict__ woutbf)
{
    int i = (blockIdx.x * 256 + threadIdx.x) * 8;
    if (i < SX) { stage8_cvt(xbf + i, x + i); return; }
    i -= SX;
    if (i < SW) { stage8_cvt(wcat + i, wqkv + i); return; }
    i -= SW;
    if (i < SL) { stage8_cvt(wcat + SW + i, w1w + i); return; }
    i -= SL;
    if (i < SL) { stage8_cvt(wcat + SW + SL + i, w2w + i); return; }
    i -= SL;
    if (i < SL) { stage8_cvt(wcat + SW + 2 * SL + i, w1r + i); return; }
    i -= SL;
    if (i < SL) { stage8_cvt(wcat + SW + 3 * SL + i, w2r + i); return; }
    i -= SL;
    if (i < SO) { stage8_cvt(woutbf + i, wout + i); }
}

// ---------------- 128x128 tile GEMM: C = A(128xK) * B(128xK)^T ----------------
__device__ __forceinline__ void gemm128_mainloop(
    const bhalf* __restrict__ A, const bhalf* __restrict__ B, int K,
    bhalf* As, bhalf* Bs, f32x4 acc[4][4])
{
    const int tid = threadIdx.x;
    const int wave = tid >> 6, lane = tid & 63;
    const int ln = lane & 15, lg = lane >> 4;
    const int wr = (wave >> 1) * 64, wc = (wave & 1) * 64;
    const int lrow = lane >> 3;
    const int lcol = (lane & 7) * 8;

    for (int kt = 0; kt < K; kt += 64) {
        __syncthreads();
#pragma unroll
        for (int i = 0; i < 4; ++i) {
            int idx = __builtin_amdgcn_readfirstlane(wave * 4 + i);
            GLD16(A + (size_t)(idx * 8 + lrow) * K + kt + lcol, As + idx * 512);
            GLD16(B + (size_t)(idx * 8 + lrow) * K + kt + lcol, Bs + idx * 512);
        }
        __syncthreads();
#pragma unroll
        for (int ks = 0; ks < 2; ++ks) {
            bf16x8 af[4], bfr[4];
#pragma unroll
            for (int mt = 0; mt < 4; ++mt)
                af[mt] = load_bf16x8(As + (wr + mt * 16 + ln) * 64 + ks * 32 + lg * 8);
#pragma unroll
            for (int nt = 0; nt < 4; ++nt)
                bfr[nt] = load_bf16x8(Bs + (wc + nt * 16 + ln) * 64 + ks * 32 + lg * 8);
#pragma unroll
            for (int mt = 0; mt < 4; ++mt)
#pragma unroll
                for (int nt = 0; nt < 4; ++nt)
                    acc[mt][nt] = __builtin_amdgcn_mfma_f32_16x16x32_bf16(af[mt], bfr[nt], acc[mt][nt], 0, 0, 0);
        }
    }
}

// fused qkv + lines projection: B = [w_qkv(3072); w1w;w2w;w1r;w2r(256)] rows, N=3328
// Q is pre-scaled by 0.125*log2(e) so attn scores are already in log2 domain.
// XCD-chunked relabel (T1): dispatch round-robins linear id across 8 XCDs;
// remap so each XCD owns a CONTIGUOUS y-chunk (~4 weight panels ~1MB stays
// resident in its 4MB L2 instead of cycling all 26 panels = 6.6MB).
// 832 = 8*104 exactly -> bijective.
__global__ __launch_bounds__(256) void qkv_lines_gemm128(
    const bhalf* __restrict__ x, const bhalf* __restrict__ wcat, const float* __restrict__ bqkv,
    bhalf* __restrict__ qo, bhalf* __restrict__ ko, bhalf* __restrict__ vt,
    float* __restrict__ proj)
{
    __shared__ bhalf As[128 * 64];
    __shared__ bhalf Bs[128 * 64];
    const int lid = blockIdx.y * 32 + blockIdx.x;      // dispatch-linear id
    const int wgid = (lid & 7) * 104 + (lid >> 3);     // XCD-chunked, bijective
    const int bx2 = wgid & 31, by2 = wgid >> 5;        // x' in [0,32), y' in [0,26)
    f32x4 acc[4][4] = {};
    gemm128_mainloop(x + (size_t)bx2 * 128 * D_DIM,
                     wcat + (size_t)by2 * 128 * D_DIM, D_DIM, As, Bs, acc);
    const int wave = threadIdx.x >> 6, lane = threadIdx.x & 63;
    const int ln = lane & 15, lg = lane >> 4;
    const int wr = (wave >> 1) * 64, wc = (wave & 1) * 64;
    const int trip = (by2 * 128) >> 10;   // uniform per block (128 | 1024)

    if (trip == 2) {
        // v^T: pack 4 consecutive-t values -> one 8B store per (mt,nt)
#pragma unroll
        for (int nt = 0; nt < 4; ++nt) {
            int n = by2 * 128 + wc + nt * 16 + ln;
            float bias = bqkv[n];
            int h = (n >> 6) & 15, d = n & 63;
#pragma unroll
            for (int mt = 0; mt < 4; ++mt) {
                int tok0 = bx2 * 128 + wr + mt * 16 + lg * 4;
                int b = tok0 >> 11, t0 = tok0 & (T_DIM - 1);
                bh4 pk;
#pragma unroll
                for (int r = 0; r < 4; ++r)
                    pk.v[r] = __float2bfloat16(acc[mt][nt][r] + bias);
                *(uint2*)&vt[(((size_t)(b * H_DIM + h)) * DH + d) * T_DIM + t0] =
                    __builtin_bit_cast(uint2, pk);
            }
        }
    } else {
#pragma unroll
        for (int nt = 0; nt < 4; ++nt) {
            int n = by2 * 128 + wc + nt * 16 + ln;
            int h = (n >> 6) & 15, d = n & 63;
            float bias = (trip < 3) ? bqkv[n] : 0.f;
#pragma unroll
            for (int mt = 0; mt < 4; ++mt)
#pragma unroll
                for (int r = 0; r < 4; ++r) {
                    int tok = bx2 * 128 + wr + mt * 16 + lg * 4 + r;
                    int b = tok >> 11, t = tok & (T_DIM - 1);
                    float y = acc[mt][nt][r] + bias;
                    if (trip == 0) {
                        // 0.125 * log2(e)
                        qo[(((size_t)(b * H_DIM + h)) * T_DIM + t) * DH + d] = __float2bfloat16(y * 0.18033688f);
                    } else if (trip == 1) {
                        ko[(((size_t)(b * H_DIM + h)) * T_DIM + t) * DH + d] = __float2bfloat16(y);
                    } else {
                        proj[(size_t)tok * 256 + (n - 3072)] = y;
                    }
                }
        }
    }
}

// out projection: 64x64 tile (R0-proven). grid (64,16) = 1024 blocks = 4/CU --
// inter-block overlap hides the barrier drains (the 128^2 variant's 256 blocks
// = 1 block/CU had none and was ~3us slower; R4/R5 totals). XCD-chunked
// relabel: 1024 = 8*128 exactly -> each XCD owns 2 contiguous weight panels.
__global__ __launch_bounds__(256) void out_gemm64(
    const bhalf* __restrict__ a, const bhalf* __restrict__ w, const float* __restrict__ bo,
    float* __restrict__ out)
{
    __shared__ bhalf As[64 * 64];
    __shared__ bhalf Bs[64 * 64];
    const int lid = blockIdx.y * 64 + blockIdx.x;
    const int wgid = (lid & 7) * 128 + (lid >> 3);
    const int bx2 = wgid & 63, by2 = wgid >> 6;        // x' in [0,64), y' in [0,16)
    const int tid = threadIdx.x;
    const int wave = tid >> 6, lane = tid & 63;
    const int ln = lane & 15, lg = lane >> 4;
    const int lrow = lane >> 3;
    const int lcol = (lane & 7) * 8;
    const bhalf* A = a + (size_t)bx2 * 64 * D_DIM;
    const bhalf* B = w + (size_t)by2 * 64 * D_DIM;
    f32x4 acc[4] = {};

    for (int kt = 0; kt < D_DIM; kt += 64) {
        __syncthreads();
#pragma unroll
        for (int i = 0; i < 2; ++i) {
            int idx = __builtin_amdgcn_readfirstlane(wave * 2 + i);
            GLD16(A + (size_t)(idx * 8 + lrow) * D_DIM + kt + lcol, As + idx * 512);
            GLD16(B + (size_t)(idx * 8 + lrow) * D_DIM + kt + lcol, Bs + idx * 512);
        }
        __syncthreads();
#pragma unroll
        for (int ks = 0; ks < 2; ++ks) {
            bf16x8 af = load_bf16x8(As + (wave * 16 + ln) * 64 + ks * 32 + lg * 8);
#pragma unroll
            for (int nt = 0; nt < 4; ++nt) {
                bf16x8 bfr = load_bf16x8(Bs + (nt * 16 + ln) * 64 + ks * 32 + lg * 8);
                acc[nt] = __builtin_amdgcn_mfma_f32_16x16x32_bf16(af, bfr, acc[nt], 0, 0, 0);
            }
        }
    }
#pragma unroll
    for (int nt = 0; nt < 4; ++nt) {
        int n = by2 * 64 + nt * 16 + ln;
        float bias = bo[n];
#pragma unroll
        for (int r = 0; r < 4; ++r) {
            int tok = bx2 * 64 + wave * 16 + lg * 4 + r;
            out[(size_t)tok * D_DIM + n] = acc[nt][r] + bias;
        }
    }
}

__global__ __launch_bounds__(256) void build_lines(
    const float* __restrict__ proj, const float* __restrict__ bias_scale,
    const float* __restrict__ decay_logits,
    bhalf* __restrict__ read8, bhalf* __restrict__ jw8)
{
    int id = blockIdx.x * 256 + threadIdx.x;
    int tok = id >> 4, h = id & 15;
    int b = tok >> 11, t = tok & (T_DIM - 1);
    const float* pr = proj + (size_t)tok * 256;

    float p1[4], p2[4], r1[4], r2[4];
#pragma unroll
    for (int i = 0; i < 4; ++i) {
        p1[i] = (t > 0) ? pr[-256 + h * 4 + i] : 0.f;
        p2[i] = pr[64 + h * 4 + i];
        r1[i] = pr[128 + h * 4 + i];
        r2[i] = pr[192 + h * 4 + i];
    }
    float Lw[6], Lr[6];
    {
        Lw[0] = p1[0] * p2[1] - p1[1] * p2[0];
        Lw[1] = p1[0] * p2[2] - p1[2] * p2[0];
        Lw[2] = p1[0] * p2[3] - p1[3] * p2[0];
        Lw[3] = p1[1] * p2[2] - p1[2] * p2[1];
        Lw[4] = p1[1] * p2[3] - p1[3] * p2[1];
        Lw[5] = p1[2] * p2[3] - p1[3] * p2[2];
        float n2 = 0.f;
#pragma unroll
        for (int j = 0; j < 6; ++j) n2 += Lw[j] * Lw[j];
        float inv = 1.f / fmaxf(sqrtf(n2), 1e-12f);
#pragma unroll
        for (int j = 0; j < 6; ++j) Lw[j] *= inv;
    }
    {
        Lr[0] = r1[0] * r2[1] - r1[1] * r2[0];
        Lr[1] = r1[0] * r2[2] - r1[2] * r2[0];
        Lr[2] = r1[0] * r2[3] - r1[3] * r2[0];
        Lr[3] = r1[1] * r2[2] - r1[2] * r2[1];
        Lr[4] = r1[1] * r2[3] - r1[3] * r2[1];
        Lr[5] = r1[2] * r2[3] - r1[3] * r2[2];
        float n2 = 0.f;
#pragma unroll
        for (int j = 0; j < 6; ++j) n2 += Lr[j] * Lr[j];
        float inv = 1.f / fmaxf(sqrtf(n2), 1e-12f);
#pragma unroll
        for (int j = 0; j < 6; ++j) Lr[j] *= inv;
    }
    float decay = 1.f / (1.f + __expf(-decay_logits[h]));
    float l2d = log2f(decay);
    float bs = bias_scale[h] * exp2f(-(float)t * l2d);
    size_t base = (((size_t)(b * H_DIM + h)) * T_DIM + t) * 8;
    read8[base + 0] = __float2bfloat16(Lr[0]);
    read8[base + 1] = __float2bfloat16(Lr[1]);
    read8[base + 2] = __float2bfloat16(Lr[2]);
    read8[base + 3] = __float2bfloat16(Lr[3]);
    read8[base + 4] = __float2bfloat16(Lr[4]);
    read8[base + 5] = __float2bfloat16(Lr[5]);
    read8[base + 6] = __float2bfloat16(0.f);
    read8[base + 7] = __float2bfloat16(0.f);
    jw8[base + 0] = __float2bfloat16(Lw[5] * bs);
    jw8[base + 1] = __float2bfloat16(-Lw[4] * bs);
    jw8[base + 2] = __float2bfloat16(Lw[3] * bs);
    jw8[base + 3] = __float2bfloat16(Lw[2] * bs);
    jw8[base + 4] = __float2bfloat16(-Lw[1] * bs);
    jw8[base + 5] = __float2bfloat16(Lw[0] * bs);
    jw8[base + 6] = __float2bfloat16(0.f);
    jw8[base + 7] = __float2bfloat16(0.f);
}

// softmax tile step: scores -> P (packed bf16x2 stores), k-cols = kb+2*ln (+1)
// z is already in log2 domain (Q pre-scaled by 0.125*log2e); aq carries log2e.
// Single v_exp_f32 per element via __builtin_amdgcn_exp2f.
template<bool DIAG>
__device__ __forceinline__ void tile_step(
    const f32x4& z0, const f32x4& z1, const f32x4& i0, const f32x4& i1,
    int rq, int kb, const float* aq, int lg, int ln, bhalf* pl, float* lp)
{
#pragma unroll
    for (int r = 0; r < 4; ++r) {
        float p0, p1;
        if (DIAG) {
            int diff0 = rq + lg * 4 + r - (kb + 2 * ln);
            float s0 = z0[r] + ((diff0 > 0) ? i0[r] * aq[r] : 0.f);
            p0 = (diff0 < 0) ? 0.f : __builtin_amdgcn_exp2f(s0);
            int diff1 = diff0 - 1;
            float s1 = z1[r] + ((diff1 > 0) ? i1[r] * aq[r] : 0.f);
            p1 = (diff1 < 0) ? 0.f : __builtin_amdgcn_exp2f(s1);
        } else {
            p0 = __builtin_amdgcn_exp2f(fmaf(i0[r], aq[r], z0[r]));
            p1 = __builtin_amdgcn_exp2f(fmaf(i1[r], aq[r], z1[r]));
        }
        bf16x2 h2;
        h2.x = (__bf16)p0;
        h2.y = (__bf16)p1;
        *(unsigned int*)&pl[(lg * 4 + r) * 40 + 2 * ln] = __builtin_bit_cast(unsigned int, h2);
        lp[r] += p0 + p1;
    }
}

// Attention, antithetic-paired, paired-k, fast/diag paths.
// 1-D grid (2048) with XCD-partitioned decode: xcd = bx&7 owns 4 (b,h) pairs,
// so each head's 512KB K/V stays in ONE XCD's 4MB L2 (latency: HBM->L2 hits).
// Best-known config (R0 structure + exp2-domain softmax, R5 barrier removal
// neutral-kept-out). R1/R3 prefetch, R2 setprio: regressions, removed.
__global__ __launch_bounds__(256) void attn_kernel(
    const bhalf* __restrict__ q, const bhalf* __restrict__ k, const bhalf* __restrict__ vt,
    const bhalf* __restrict__ read8, const bhalf* __restrict__ jw8,
    const float* __restrict__ decay_logits, bhalf* __restrict__ attn_out)
{
    __shared__ float sm[4352];   // 17408 B
    const int wave = threadIdx.x >> 6, lane = threadIdx.x & 63;
    const int ln = lane & 15, lg = lane >> 4;
    const int bx = blockIdx.x;             // 0..2047
    const int xcd = bx & 7;
    const int slot = bx >> 3;              // 0..255
    const int hbid = xcd * 4 + (slot >> 6);  // 0..31
    const int h = hbid & 15, b = hbid >> 4;
    const int qa = slot & 63;
    const int qb = 127 - qa;
    const int rqa = qa * 16, rqb = qb * 16;
    const size_t hb = (size_t)(b * H_DIM + h);
    const bhalf* qh = q + hb * T_DIM * DH;
    const bhalf* kh = k + hb * T_DIM * DH;
    const bhalf* vh = vt + hb * DH * T_DIM;
    const bhalf* r8 = read8 + hb * T_DIM * 8;
    const bhalf* j8 = jw8 + hb * T_DIM * 8;

    bhalf* plA = (bhalf*)sm + wave * 640;
    bhalf* plB = (bhalf*)sm + 2560 + wave * 640;

    bf16x8 zf = zero_bf16x8();
    bf16x8 qA0 = load_bf16x8(qh + (rqa + ln) * DH + lg * 8);
    bf16x8 qA1 = load_bf16x8(qh + (rqa + ln) * DH + 32 + lg * 8);
    bf16x8 qB0 = load_bf16x8(qh + (rqb + ln) * DH + lg * 8);
    bf16x8 qB1 = load_bf16x8(qh + (rqb + ln) * DH + 32 + lg * 8);
    bf16x8 rfA = (lane < 16) ? load_bf16x8(r8 + (size_t)(rqa + ln) * 8) : zf;
    bf16x8 rfB = (lane < 16) ? load_bf16x8(r8 + (size_t)(rqb + ln) * 8) : zf;

    float decay = 1.f / (1.f + __expf(-decay_logits[h]));
    float l2d = log2f(decay);
    const float LOG2E = 1.44269504f;
    float aqA[4], aqB[4];
#pragma unroll
    for (int r = 0; r < 4; ++r) {
        aqA[r] = LOG2E * __builtin_amdgcn_exp2f((float)(rqa + lg * 4 + r) * l2d);
        aqB[r] = LOG2E * __builtin_amdgcn_exp2f((float)(rqb + lg * 4 + r) * l2d);
    }

    f32x4 oA[4] = {}, oB[4] = {};
    float lpA[4] = {0.f, 0.f, 0.f, 0.f}, lpB[4] = {0.f, 0.f, 0.f, 0.f};

    const int nca = qa / 2 + 1, ncb = qb / 2 + 1;
    for (int c = wave; c < ncb; c += 4) {
        const int kb = c * 32;
        bf16x8 k00 = load_bf16x8(kh + (kb + 2 * ln) * DH + lg * 8);
        bf16x8 k01 = load_bf16x8(kh + (kb + 2 * ln) * DH + 32 + lg * 8);
        bf16x8 k10 = load_bf16x8(kh + (kb + 2 * ln + 1) * DH + lg * 8);
        bf16x8 k11 = load_bf16x8(kh + (kb + 2 * ln + 1) * DH + 32 + lg * 8);
        bf16x8 j0 = (lane < 16) ? load_bf16x8(j8 + (size_t)(kb + 2 * ln) * 8) : zf;
        bf16x8 j1 = (lane < 16) ? load_bf16x8(j8 + (size_t)(kb + 2 * ln + 1) * 8) : zf;
        bf16x8 vf0 = load_bf16x8(vh + (size_t)(ln) * T_DIM + kb + lg * 8);
        bf16x8 vf1 = load_bf16x8(vh + (size_t)(16 + ln) * T_DIM + kb + lg * 8);
        bf16x8 vf2 = load_bf16x8(vh + (size_t)(32 + ln) * T_DIM + kb + lg * 8);
        bf16x8 vf3 = load_bf16x8(vh + (size_t)(48 + ln) * T_DIM + kb + lg * 8);
        const bool doA = (c < nca);

        {
            f32x4 z0 = {}, z1 = {}, i0 = {}, i1 = {};
            z0 = __builtin_amdgcn_mfma_f32_16x16x32_bf16(qB0, k00, z0, 0, 0, 0);
            z0 = __builtin_amdgcn_mfma_f32_16x16x32_bf16(qB1, k01, z0, 0, 0, 0);
            i0 = __builtin_amdgcn_mfma_f32_16x16x32_bf16(rfB, j0, i0, 0, 0, 0);
            z1 = __builtin_amdgcn_mfma_f32_16x16x32_bf16(qB0, k10, z1, 0, 0, 0);
            z1 = __builtin_amdgcn_mfma_f32_16x16x32_bf16(qB1, k11, z1, 0, 0, 0);
            i1 = __builtin_amdgcn_mfma_f32_16x16x32_bf16(rfB, j1, i1, 0, 0, 0);
            if (c == ncb - 1) tile_step<true >(z0, z1, i0, i1, rqb, kb, aqB, lg, ln, plB, lpB);
            else              tile_step<false>(z0, z1, i0, i1, rqb, kb, aqB, lg, ln, plB, lpB);
        }
        if (doA) {
            f32x4 z0 = {}, z1 = {}, i0 = {}, i1 = {};
            z0 = __builtin_amdgcn_mfma_f32_16x16x32_bf16(qA0, k00, z0, 0, 0, 0);
            z0 = __builtin_amdgcn_mfma_f32_16x16x32_bf16(qA1, k01, z0, 0, 0, 0);
            i0 = __builtin_amdgcn_mfma_f32_16x16x32_bf16(rfA, j0, i0, 0, 0, 0);
            z1 = __builtin_amdgcn_mfma_f32_16x16x32_bf16(qA0, k10, z1, 0, 0, 0);
            z1 = __builtin_amdgcn_mfma_f32_16x16x32_bf16(qA1, k11, z1, 0, 0, 0);
            i1 = __builtin_amdgcn_mfma_f32_16x16x32_bf16(rfA, j1, i1, 0, 0, 0);
            if (c == nca - 1) tile_step<true >(z0, z1, i0, i1, rqa, kb, aqA, lg, ln, plA, lpA);
            else              tile_step<false>(z0, z1, i0, i1, rqa, kb, aqA, lg, ln, plA, lpA);
        }
        {
            bf16x8 pf = load_bf16x8(plB + ln * 40 + lg * 8);
            oB[0] = __builtin_amdgcn_mfma_f32_16x16x32_bf16(pf, vf0, oB[0], 0, 0, 0);
            oB[1] = __builtin_amdgcn_mfma_f32_16x16x32_bf16(pf, vf1, oB[1], 0, 0, 0);
            oB[2] = __builtin_amdgcn_mfma_f32_16x16x32_bf16(pf, vf2, oB[2], 0, 0, 0);
            oB[3] = __builtin_amdgcn_mfma_f32_16x16x32_bf16(pf, vf3, oB[3], 0, 0, 0);
        }
        if (doA) {
            bf16x8 pf = load_bf16x8(plA + ln * 40 + lg * 8);
            oA[0] = __builtin_amdgcn_mfma_f32_16x16x32_bf16(pf, vf0, oA[0], 0, 0, 0);
            oA[1] = __builtin_amdgcn_mfma_f32_16x16x32_bf16(pf, vf1, oA[1], 0, 0, 0);
            oA[2] = __builtin_amdgcn_mfma_f32_16x16x32_bf16(pf, vf2, oA[2], 0, 0, 0);
            oA[3] = __builtin_amdgcn_mfma_f32_16x16x32_bf16(pf, vf3, oA[3], 0, 0, 0);
        }
    }

#pragma unroll
    for (int r = 0; r < 4; ++r) {
#pragma unroll
        for (int off = 1; off < 16; off <<= 1) {
            lpA[r] += __shfl_xor(lpA[r], off, 16);
            lpB[r] += __shfl_xor(lpB[r], off, 16);
        }
    }

    const int row = threadIdx.x >> 4;
    const int c4 = (threadIdx.x & 15) * 4;

    __syncthreads();
#pragma unroll
    for (int r = 0; r < 4; ++r) {
        if (ln == 0) sm[wave * 1088 + (lg * 4 + r) * 68 + 64] = lpA[r];
#pragma unroll
        for (int nt = 0; nt < 4; ++nt)
            sm[wave * 1088 + (lg * 4 + r) * 68 + nt * 16 + ln] = oA[nt][r];
    }
    __syncthreads();
    {
        float l = 0.f;
#pragma unroll
        for (int w = 0; w < 4; ++w) l += sm[w * 1088 + row * 68 + 64];
        float4 acc = {0.f, 0.f, 0.f, 0.f};
#pragma unroll
        for (int w = 0; w < 4; ++w) {
            float4 t = *(const float4*)&sm[w * 1088 + row * 68 + c4];
            acc.x += t.x; acc.y += t.y; acc.z += t.z; acc.w += t.w;
        }
        float invl = 1.f / l;
        bh4 pk;
        pk.v[0] = __float2bfloat16(acc.x * invl);
        pk.v[1] = __float2bfloat16(acc.y * invl);
        pk.v[2] = __float2bfloat16(acc.z * invl);
        pk.v[3] = __float2bfloat16(acc.w * invl);
        size_t tok = (size_t)b * T_DIM + rqa + row;
        *(uint2*)&attn_out[tok * D_DIM + h * DH + c4] = __builtin_bit_cast(uint2, pk);
    }

    __syncthreads();
#pragma unroll
    for (int r = 0; r < 4; ++r) {
        if (ln == 0) sm[wave * 1088 + (lg * 4 + r) * 68 + 64] = lpB[r];
#pragma unroll
        for (int nt = 0; nt < 4; ++nt)
            sm[wave * 1088 + (lg * 4 + r) * 68 + nt * 16 + ln] = oB[nt][r];
    }
    __syncthreads();
    {
        float l = 0.f;
#pragma unroll
        for (int w = 0; w < 4; ++w) l += sm[w * 1088 + row * 68 + 64];
        float4 acc = {0.f, 0.f, 0.f, 0.f};
#pragma unroll
        for (int w = 0; w < 4; ++w) {
            float4 t = *(const float4*)&sm[w * 1088 + row * 68 + c4];
            acc.x += t.x; acc.y += t.y; acc.z += t.z; acc.w += t.w;
        }
        float invl = 1.f / l;
        bh4 pk;
        pk.v[0] = __float2bfloat16(acc.x * invl);
        pk.v[1] = __float2bfloat16(acc.y * invl);
        pk.v[2] = __float2bfloat16(acc.z * invl);
        pk.v[3] = __float2bfloat16(acc.w * invl);
        size_t tok = (size_t)b * T_DIM + rqb + row;
        *(uint2*)&attn_out[tok * D_DIM + h * DH + c4] = __builtin_bit_cast(uint2, pk);
    }
}

extern "C" void kernel_launch(void* const* d_in, const int* in_sizes, int n_in,
                              void* d_out, int out_size, void* d_ws, size_t ws_size,
                              hipStream_t stream)
{
    const float* x    = (const float*)d_in[0];
    const float* wqkv = (const float*)d_in[1];
    const float* bqkv = (const float*)d_in[2];
    const float* w1w  = (const float*)d_in[3];
    const float* w2w  = (const float*)d_in[4];
    const float* w1r  = (const float*)d_in[5];
    const float* w2r  = (const float*)d_in[6];
    const float* wout = (const float*)d_in[7];
    const float* bout = (const float*)d_in[8];
    const float* dlog = (const float*)d_in[9];
    const float* bsc  = (const float*)d_in[10];
    float* out = (float*)d_out;

    char* ws = (char*)d_ws;
    bhalf* qb    = (bhalf*)(ws);                 // [B,H,T,64] bf16   8388608 B
    bhalf* kbuf  = (bhalf*)(ws + 8388608);       // [B,H,T,64] bf16   8388608 B
    bhalf* vtb   = (bhalf*)(ws + 16777216);      // [B,H,64,T] bf16   8388608 B
    bhalf* r8    = (bhalf*)(ws + 25165824);      // [B,H,T,8]  bf16   1048576 B
    bhalf* j8    = (bhalf*)(ws + 26214400);      // [B,H,T,8]  bf16   1048576 B
    float* proj  = (float*)(ws + 27262976);      // [B*T,256]  f32    4194304 B
    bhalf* ao    = (bhalf*)(ws + 31457280);      // [B*T,1024] bf16   8388608 B
    bhalf* woutbf = (bhalf*)(ws + 39845888);     // [1024,1024] bf16  2097152 B

    bhalf* xbf  = (bhalf*)d_out;                      //  8388608 B
    bhalf* wcat = (bhalf*)((char*)d_out + 8388608);   //  6815744 B (3328x1024)

    cvt_all<<<4224, 256, 0, stream>>>(x, wqkv, w1w, w2w, w1r, w2r, wout, xbf, wcat, woutbf);
    qkv_lines_gemm128<<<dim3(32, 26), 256, 0, stream>>>(xbf, wcat, bqkv, qb, kbuf, vtb, proj);
    build_lines<<<256, 256, 0, stream>>>(proj, bsc, dlog, r8, j8);
    attn_kernel<<<2048, 256, 0, stream>>>(qb, kbuf, vtb, r8, j8, dlog, ao);
    out_gemm64<<<dim3(64, 16), 256, 0, stream>>>(ao, woutbf, bout, out);
}

// Round 7
// 265.633 us; speedup vs baseline: 1.0856x; 1.0856x over previous
//
#include <hip/hip_runtime.h>
#include <hip/hip_bf16.h>

using bhalf = __hip_bfloat16;
typedef __bf16 bf16x8 __attribute__((ext_vector_type(8)));
typedef __bf16 bf16x2 __attribute__((ext_vector_type(2)));
typedef float f32x4 __attribute__((ext_vector_type(4)));

#define B_DIM 2
#define T_DIM 2048
#define D_DIM 1024
#define H_DIM 16
#define DH 64

struct bh8 { bhalf v[8]; };
struct bh4 { bhalf v[4]; };

__device__ __forceinline__ bf16x8 load_bf16x8(const bhalf* p) {
    return __builtin_bit_cast(bf16x8, *(const uint4*)p);
}
__device__ __forceinline__ bf16x8 zero_bf16x8() {
    uint4 z; z.x = 0; z.y = 0; z.z = 0; z.w = 0;
    return __builtin_bit_cast(bf16x8, z);
}
__device__ __forceinline__ void stage8_cvt(bhalf* dst, const float* src) {
    float4 a = *(const float4*)src;
    float4 b = *(const float4*)(src + 4);
    bh8 t;
    t.v[0] = __float2bfloat16(a.x); t.v[1] = __float2bfloat16(a.y);
    t.v[2] = __float2bfloat16(a.z); t.v[3] = __float2bfloat16(a.w);
    t.v[4] = __float2bfloat16(b.x); t.v[5] = __float2bfloat16(b.y);
    t.v[6] = __float2bfloat16(b.z); t.v[7] = __float2bfloat16(b.w);
    *(uint4*)dst = __builtin_bit_cast(uint4, t);
}

// async 16B global -> LDS (wave-uniform LDS base + lane*16)
#define GLD16(gp, lp) __builtin_amdgcn_global_load_lds( \
    (const __attribute__((address_space(1))) void*)(gp), \
    (__attribute__((address_space(3))) void*)(lp), 16, 0, 0)

// Segment sizes (elements)
#define SX  4194304
#define SW  3145728
#define SL  65536
#define SO  1048576
__global__ __launch_bounds__(256) void cvt_all(
    const float* __restrict__ x, const float* __restrict__ wqkv,
    const float* __restrict__ w1w, const float* __restrict__ w2w,
    const float* __restrict__ w1r, const float* __restrict__ w2r,
    const float* __restrict__ wout,
    bhalf* __restrict__ xbf, bhalf* __restrict__ wcat, bhalf* __restrict__ woutbf)
{
    int i = (blockIdx.x * 256 + threadIdx.x) * 8;
    if (i < SX) { stage8_cvt(xbf + i, x + i); return; }
    i -= SX;
    if (i < SW) { stage8_cvt(wcat + i, wqkv + i); return; }
    i -= SW;
    if (i < SL) { stage8_cvt(wcat + SW + i, w1w + i); return; }
    i -= SL;
    if (i < SL) { stage8_cvt(wcat + SW + SL + i, w2w + i); return; }
    i -= SL;
    if (i < SL) { stage8_cvt(wcat + SW + 2 * SL + i, w1r + i); return; }
    i -= SL;
    if (i < SL) { stage8_cvt(wcat + SW + 3 * SL + i, w2r + i); return; }
    i -= SL;
    if (i < SO) { stage8_cvt(woutbf + i, wout + i); }
}

// ---------------- 128x128 tile GEMM: C = A(128xK) * B(128xK)^T ----------------
__device__ __forceinline__ void gemm128_mainloop(
    const bhalf* __restrict__ A, const bhalf* __restrict__ B, int K,
    bhalf* As, bhalf* Bs, f32x4 acc[4][4])
{
    const int tid = threadIdx.x;
    const int wave = tid >> 6, lane = tid & 63;
    const int ln = lane & 15, lg = lane >> 4;
    const int wr = (wave >> 1) * 64, wc = (wave & 1) * 64;
    const int lrow = lane >> 3;
    const int lcol = (lane & 7) * 8;

    for (int kt = 0; kt < K; kt += 64) {
        __syncthreads();
#pragma unroll
        for (int i = 0; i < 4; ++i) {
            int idx = __builtin_amdgcn_readfirstlane(wave * 4 + i);
            GLD16(A + (size_t)(idx * 8 + lrow) * K + kt + lcol, As + idx * 512);
            GLD16(B + (size_t)(idx * 8 + lrow) * K + kt + lcol, Bs + idx * 512);
        }
        __syncthreads();
#pragma unroll
        for (int ks = 0; ks < 2; ++ks) {
            bf16x8 af[4], bfr[4];
#pragma unroll
            for (int mt = 0; mt < 4; ++mt)
                af[mt] = load_bf16x8(As + (wr + mt * 16 + ln) * 64 + ks * 32 + lg * 8);
#pragma unroll
            for (int nt = 0; nt < 4; ++nt)
                bfr[nt] = load_bf16x8(Bs + (wc + nt * 16 + ln) * 64 + ks * 32 + lg * 8);
#pragma unroll
            for (int mt = 0; mt < 4; ++mt)
#pragma unroll
                for (int nt = 0; nt < 4; ++nt)
                    acc[mt][nt] = __builtin_amdgcn_mfma_f32_16x16x32_bf16(af[mt], bfr[nt], acc[mt][nt], 0, 0, 0);
        }
    }
}

// fused qkv + lines projection: B = [w_qkv(3072); w1w;w2w;w1r;w2r(256)] rows, N=3328
// Q is pre-scaled by 0.125*log2(e) so attn scores are already in log2 domain.
// (R6 XCD swizzle reverted: neutral-to-negative.)
__global__ __launch_bounds__(256) void qkv_lines_gemm128(
    const bhalf* __restrict__ x, const bhalf* __restrict__ wcat, const float* __restrict__ bqkv,
    bhalf* __restrict__ qo, bhalf* __restrict__ ko, bhalf* __restrict__ vt,
    float* __restrict__ proj)
{
    __shared__ bhalf As[128 * 64];
    __shared__ bhalf Bs[128 * 64];
    f32x4 acc[4][4] = {};
    gemm128_mainloop(x + (size_t)blockIdx.x * 128 * D_DIM,
                     wcat + (size_t)blockIdx.y * 128 * D_DIM, D_DIM, As, Bs, acc);
    const int wave = threadIdx.x >> 6, lane = threadIdx.x & 63;
    const int ln = lane & 15, lg = lane >> 4;
    const int wr = (wave >> 1) * 64, wc = (wave & 1) * 64;
    const int trip = (blockIdx.y * 128) >> 10;   // uniform per block (128 | 1024)

    if (trip == 2) {
        // v^T: pack 4 consecutive-t values -> one 8B store per (mt,nt)
#pragma unroll
        for (int nt = 0; nt < 4; ++nt) {
            int n = blockIdx.y * 128 + wc + nt * 16 + ln;
            float bias = bqkv[n];
            int h = (n >> 6) & 15, d = n & 63;
#pragma unroll
            for (int mt = 0; mt < 4; ++mt) {
                int tok0 = blockIdx.x * 128 + wr + mt * 16 + lg * 4;
                int b = tok0 >> 11, t0 = tok0 & (T_DIM - 1);
                bh4 pk;
#pragma unroll
                for (int r = 0; r < 4; ++r)
                    pk.v[r] = __float2bfloat16(acc[mt][nt][r] + bias);
                *(uint2*)&vt[(((size_t)(b * H_DIM + h)) * DH + d) * T_DIM + t0] =
                    __builtin_bit_cast(uint2, pk);
            }
        }
    } else {
#pragma unroll
        for (int nt = 0; nt < 4; ++nt) {
            int n = blockIdx.y * 128 + wc + nt * 16 + ln;
            int h = (n >> 6) & 15, d = n & 63;
            float bias = (trip < 3) ? bqkv[n] : 0.f;
#pragma unroll
            for (int mt = 0; mt < 4; ++mt)
#pragma unroll
                for (int r = 0; r < 4; ++r) {
                    int tok = blockIdx.x * 128 + wr + mt * 16 + lg * 4 + r;
                    int b = tok >> 11, t = tok & (T_DIM - 1);
                    float y = acc[mt][nt][r] + bias;
                    if (trip == 0) {
                        // 0.125 * log2(e)
                        qo[(((size_t)(b * H_DIM + h)) * T_DIM + t) * DH + d] = __float2bfloat16(y * 0.18033688f);
                    } else if (trip == 1) {
                        ko[(((size_t)(b * H_DIM + h)) * T_DIM + t) * DH + d] = __float2bfloat16(y);
                    } else {
                        proj[(size_t)tok * 256 + (n - 3072)] = y;
                    }
                }
        }
    }
}

// 64x64 bf16 GEMM with global_load_lds staging (out projection; 1024 blocks,
// 4 blocks/CU -- R0-proven; 128^2 variant's 1 block/CU was slower).
__global__ __launch_bounds__(256) void out_gemm64(
    const bhalf* __restrict__ a, const bhalf* __restrict__ w, const float* __restrict__ bo,
    float* __restrict__ out)
{
    __shared__ bhalf As[64 * 64];
    __shared__ bhalf Bs[64 * 64];
    const int tid = threadIdx.x;
    const int wave = tid >> 6, lane = tid & 63;
    const int ln = lane & 15, lg = lane >> 4;
    const int lrow = lane >> 3;
    const int lcol = (lane & 7) * 8;
    const bhalf* A = a + (size_t)blockIdx.x * 64 * D_DIM;
    const bhalf* B = w + (size_t)blockIdx.y * 64 * D_DIM;
    f32x4 acc[4] = {};

    for (int kt = 0; kt < D_DIM; kt += 64) {
        __syncthreads();
#pragma unroll
        for (int i = 0; i < 2; ++i) {
            int idx = __builtin_amdgcn_readfirstlane(wave * 2 + i);
            GLD16(A + (size_t)(idx * 8 + lrow) * D_DIM + kt + lcol, As + idx * 512);
            GLD16(B + (size_t)(idx * 8 + lrow) * D_DIM + kt + lcol, Bs + idx * 512);
        }
        __syncthreads();
#pragma unroll
        for (int ks = 0; ks < 2; ++ks) {
            bf16x8 af = load_bf16x8(As + (wave * 16 + ln) * 64 + ks * 32 + lg * 8);
#pragma unroll
            for (int nt = 0; nt < 4; ++nt) {
                bf16x8 bfr = load_bf16x8(Bs + (nt * 16 + ln) * 64 + ks * 32 + lg * 8);
                acc[nt] = __builtin_amdgcn_mfma_f32_16x16x32_bf16(af, bfr, acc[nt], 0, 0, 0);
            }
        }
    }
#pragma unroll
    for (int nt = 0; nt < 4; ++nt) {
        int n = blockIdx.y * 64 + nt * 16 + ln;
        float bias = bo[n];
#pragma unroll
        for (int r = 0; r < 4; ++r) {
            int tok = blockIdx.x * 64 + wave * 16 + lg * 4 + r;
            out[(size_t)tok * D_DIM + n] = acc[nt][r] + bias;
        }
    }
}

__global__ __launch_bounds__(256) void build_lines(
    const float* __restrict__ proj, const float* __restrict__ bias_scale,
    const float* __restrict__ decay_logits,
    bhalf* __restrict__ read8, bhalf* __restrict__ jw8)
{
    int id = blockIdx.x * 256 + threadIdx.x;
    int tok = id >> 4, h = id & 15;
    int b = tok >> 11, t = tok & (T_DIM - 1);
    const float* pr = proj + (size_t)tok * 256;

    float p1[4], p2[4], r1[4], r2[4];
#pragma unroll
    for (int i = 0; i < 4; ++i) {
        p1[i] = (t > 0) ? pr[-256 + h * 4 + i] : 0.f;
        p2[i] = pr[64 + h * 4 + i];
        r1[i] = pr[128 + h * 4 + i];
        r2[i] = pr[192 + h * 4 + i];
    }
    float Lw[6], Lr[6];
    {
        Lw[0] = p1[0] * p2[1] - p1[1] * p2[0];
        Lw[1] = p1[0] * p2[2] - p1[2] * p2[0];
        Lw[2] = p1[0] * p2[3] - p1[3] * p2[0];
        Lw[3] = p1[1] * p2[2] - p1[2] * p2[1];
        Lw[4] = p1[1] * p2[3] - p1[3] * p2[1];
        Lw[5] = p1[2] * p2[3] - p1[3] * p2[2];
        float n2 = 0.f;
#pragma unroll
        for (int j = 0; j < 6; ++j) n2 += Lw[j] * Lw[j];
        float inv = 1.f / fmaxf(sqrtf(n2), 1e-12f);
#pragma unroll
        for (int j = 0; j < 6; ++j) Lw[j] *= inv;
    }
    {
        Lr[0] = r1[0] * r2[1] - r1[1] * r2[0];
        Lr[1] = r1[0] * r2[2] - r1[2] * r2[0];
        Lr[2] = r1[0] * r2[3] - r1[3] * r2[0];
        Lr[3] = r1[1] * r2[2] - r1[2] * r2[1];
        Lr[4] = r1[1] * r2[3] - r1[3] * r2[1];
        Lr[5] = r1[2] * r2[3] - r1[3] * r2[2];
        float n2 = 0.f;
#pragma unroll
        for (int j = 0; j < 6; ++j) n2 += Lr[j] * Lr[j];
        float inv = 1.f / fmaxf(sqrtf(n2), 1e-12f);
#pragma unroll
        for (int j = 0; j < 6; ++j) Lr[j] *= inv;
    }
    float decay = 1.f / (1.f + __expf(-decay_logits[h]));
    float l2d = log2f(decay);
    float bs = bias_scale[h] * exp2f(-(float)t * l2d);
    size_t base = (((size_t)(b * H_DIM + h)) * T_DIM + t) * 8;
    read8[base + 0] = __float2bfloat16(Lr[0]);
    read8[base + 1] = __float2bfloat16(Lr[1]);
    read8[base + 2] = __float2bfloat16(Lr[2]);
    read8[base + 3] = __float2bfloat16(Lr[3]);
    read8[base + 4] = __float2bfloat16(Lr[4]);
    read8[base + 5] = __float2bfloat16(Lr[5]);
    read8[base + 6] = __float2bfloat16(0.f);
    read8[base + 7] = __float2bfloat16(0.f);
    jw8[base + 0] = __float2bfloat16(Lw[5] * bs);
    jw8[base + 1] = __float2bfloat16(-Lw[4] * bs);
    jw8[base + 2] = __float2bfloat16(Lw[3] * bs);
    jw8[base + 3] = __float2bfloat16(Lw[2] * bs);
    jw8[base + 4] = __float2bfloat16(-Lw[1] * bs);
    jw8[base + 5] = __float2bfloat16(Lw[0] * bs);
    jw8[base + 6] = __float2bfloat16(0.f);
    jw8[base + 7] = __float2bfloat16(0.f);
}

// softmax tile step: scores -> P (packed bf16x2 stores), k-cols = kb+2*ln (+1)
// z is already in log2 domain (Q pre-scaled by 0.125*log2e); aq carries log2e.
template<bool DIAG>
__device__ __forceinline__ void tile_step(
    const f32x4& z0, const f32x4& z1, const f32x4& i0, const f32x4& i1,
    int rq, int kb, const float* aq, int lg, int ln, bhalf* pl, float* lp)
{
#pragma unroll
    for (int r = 0; r < 4; ++r) {
        float p0, p1;
        if (DIAG) {
            int diff0 = rq + lg * 4 + r - (kb + 2 * ln);
            float s0 = z0[r] + ((diff0 > 0) ? i0[r] * aq[r] : 0.f);
            p0 = (diff0 < 0) ? 0.f : __builtin_amdgcn_exp2f(s0);
            int diff1 = diff0 - 1;
            float s1 = z1[r] + ((diff1 > 0) ? i1[r] * aq[r] : 0.f);
            p1 = (diff1 < 0) ? 0.f : __builtin_amdgcn_exp2f(s1);
        } else {
            p0 = __builtin_amdgcn_exp2f(fmaf(i0[r], aq[r], z0[r]));
            p1 = __builtin_amdgcn_exp2f(fmaf(i1[r], aq[r], z1[r]));
        }
        bf16x2 h2;
        h2.x = (__bf16)p0;
        h2.y = (__bf16)p1;
        *(unsigned int*)&pl[(lg * 4 + r) * 40 + 2 * ln] = __builtin_bit_cast(unsigned int, h2);
        lp[r] += p0 + p1;
    }
}

// Attention, 4 Q-tiles per block (R7): tiles {j, 63-j, 64+j, 127-j} of one
// (b,h) -- constant total work per block, grid 1024, XCD K/V locality kept
// (xcd = bx&7 owns 4 heads). Rationale: 6 rounds of scheduling micro-opts all
// failed; kernel sits at the 1-wave/16-row structural plateau (161 TF ~= the
// m185 plateau). This amortizes the 10 K/J/V loads + addressing per k-tile
// over 4 tile_steps instead of 2. Inner machinery (tile_step, P-LDS layout,
// load set) unchanged. VGPR ~170-200 (<256 cliff); LDS 20480 B.
#define MFMA_BF16 __builtin_amdgcn_mfma_f32_16x16x32_bf16

#define QKSM(T) { \
    f32x4 z0 = {}, z1 = {}, i0 = {}, i1 = {}; \
    z0 = MFMA_BF16(q##T##0, k00, z0, 0, 0, 0); \
    z0 = MFMA_BF16(q##T##1, k01, z0, 0, 0, 0); \
    i0 = MFMA_BF16(rf##T, j0, i0, 0, 0, 0); \
    z1 = MFMA_BF16(q##T##0, k10, z1, 0, 0, 0); \
    z1 = MFMA_BF16(q##T##1, k11, z1, 0, 0, 0); \
    i1 = MFMA_BF16(rf##T, j1, i1, 0, 0, 0); \
    if (c == nc##T - 1) tile_step<true >(z0, z1, i0, i1, rq##T, kb, aq##T, lg, ln, pl##T, lp##T); \
    else                tile_step<false>(z0, z1, i0, i1, rq##T, kb, aq##T, lg, ln, pl##T, lp##T); }

#define PVSTEP(T) { \
    bf16x8 pf = load_bf16x8(pl##T + ln * 40 + lg * 8); \
    o##T[0] = MFMA_BF16(pf, vf0, o##T[0], 0, 0, 0); \
    o##T[1] = MFMA_BF16(pf, vf1, o##T[1], 0, 0, 0); \
    o##T[2] = MFMA_BF16(pf, vf2, o##T[2], 0, 0, 0); \
    o##T[3] = MFMA_BF16(pf, vf3, o##T[3], 0, 0, 0); }

#define WRITE_OUT(T) { \
    __syncthreads(); \
    _Pragma("unroll") \
    for (int r = 0; r < 4; ++r) { \
        if (ln == 0) sm[wave * 1088 + (lg * 4 + r) * 68 + 64] = lp##T[r]; \
        _Pragma("unroll") \
        for (int nt = 0; nt < 4; ++nt) \
            sm[wave * 1088 + (lg * 4 + r) * 68 + nt * 16 + ln] = o##T[nt][r]; \
    } \
    __syncthreads(); \
    { \
        float l = 0.f; \
        _Pragma("unroll") \
        for (int w = 0; w < 4; ++w) l += sm[w * 1088 + row * 68 + 64]; \
        float4 acc = {0.f, 0.f, 0.f, 0.f}; \
        _Pragma("unroll") \
        for (int w = 0; w < 4; ++w) { \
            float4 t = *(const float4*)&sm[w * 1088 + row * 68 + c4]; \
            acc.x += t.x; acc.y += t.y; acc.z += t.z; acc.w += t.w; \
        } \
        float invl = 1.f / l; \
        bh4 pk; \
        pk.v[0] = __float2bfloat16(acc.x * invl); \
        pk.v[1] = __float2bfloat16(acc.y * invl); \
        pk.v[2] = __float2bfloat16(acc.z * invl); \
        pk.v[3] = __float2bfloat16(acc.w * invl); \
        size_t tok = (size_t)b * T_DIM + rq##T + row; \
        *(uint2*)&attn_out[tok * D_DIM + h * DH + c4] = __builtin_bit_cast(uint2, pk); \
    } }

__global__ __launch_bounds__(256) void attn_kernel(
    const bhalf* __restrict__ q, const bhalf* __restrict__ k, const bhalf* __restrict__ vt,
    const bhalf* __restrict__ read8, const bhalf* __restrict__ jw8,
    const float* __restrict__ decay_logits, bhalf* __restrict__ attn_out)
{
    __shared__ float sm[5120];   // 20480 B: 4 P buffers (4x5120B); epilogue reuses
    const int wave = threadIdx.x >> 6, lane = threadIdx.x & 63;
    const int ln = lane & 15, lg = lane >> 4;
    const int bx = blockIdx.x;               // 0..1023
    const int xcd = bx & 7;
    const int slot = bx >> 3;                // 0..127
    const int hbid = xcd * 4 + (slot >> 5);  // 0..31
    const int h = hbid & 15, b = hbid >> 4;
    const int j = slot & 31;
    // four Q-tiles (16 rows each), constant total work per block
    const int tA = j, tB = 63 - j, tC = 64 + j, tD = 127 - j;
    const int rqA = tA * 16, rqB = tB * 16, rqC = tC * 16, rqD = tD * 16;
    const int ncA = (tA >> 1) + 1, ncB = (tB >> 1) + 1;
    const int ncC = (tC >> 1) + 1, ncD = (tD >> 1) + 1;
    const size_t hb = (size_t)(b * H_DIM + h);
    const bhalf* qh = q + hb * T_DIM * DH;
    const bhalf* kh = k + hb * T_DIM * DH;
    const bhalf* vh = vt + hb * DH * T_DIM;
    const bhalf* r8 = read8 + hb * T_DIM * 8;
    const bhalf* j8 = jw8 + hb * T_DIM * 8;

    bhalf* plA = (bhalf*)sm + 0 * 2560 + wave * 640;
    bhalf* plB = (bhalf*)sm + 1 * 2560 + wave * 640;
    bhalf* plC = (bhalf*)sm + 2 * 2560 + wave * 640;
    bhalf* plD = (bhalf*)sm + 3 * 2560 + wave * 640;

    bf16x8 zf = zero_bf16x8();
    bf16x8 qA0 = load_bf16x8(qh + (rqA + ln) * DH + lg * 8);
    bf16x8 qA1 = load_bf16x8(qh + (rqA + ln) * DH + 32 + lg * 8);
    bf16x8 qB0 = load_bf16x8(qh + (rqB + ln) * DH + lg * 8);
    bf16x8 qB1 = load_bf16x8(qh + (rqB + ln) * DH + 32 + lg * 8);
    bf16x8 qC0 = load_bf16x8(qh + (rqC + ln) * DH + lg * 8);
    bf16x8 qC1 = load_bf16x8(qh + (rqC + ln) * DH + 32 + lg * 8);
    bf16x8 qD0 = load_bf16x8(qh + (rqD + ln) * DH + lg * 8);
    bf16x8 qD1 = load_bf16x8(qh + (rqD + ln) * DH + 32 + lg * 8);
    bf16x8 rfA = (lane < 16) ? load_bf16x8(r8 + (size_t)(rqA + ln) * 8) : zf;
    bf16x8 rfB = (lane < 16) ? load_bf16x8(r8 + (size_t)(rqB + ln) * 8) : zf;
    bf16x8 rfC = (lane < 16) ? load_bf16x8(r8 + (size_t)(rqC + ln) * 8) : zf;
    bf16x8 rfD = (lane < 16) ? load_bf16x8(r8 + (size_t)(rqD + ln) * 8) : zf;

    float decay = 1.f / (1.f + __expf(-decay_logits[h]));
    float l2d = log2f(decay);
    const float LOG2E = 1.44269504f;
    float aqA[4], aqB[4], aqC[4], aqD[4];
#pragma unroll
    for (int r = 0; r < 4; ++r) {
        aqA[r] = LOG2E * __builtin_amdgcn_exp2f((float)(rqA + lg * 4 + r) * l2d);
        aqB[r] = LOG2E * __builtin_amdgcn_exp2f((float)(rqB + lg * 4 + r) * l2d);
        aqC[r] = LOG2E * __builtin_amdgcn_exp2f((float)(rqC + lg * 4 + r) * l2d);
        aqD[r] = LOG2E * __builtin_amdgcn_exp2f((float)(rqD + lg * 4 + r) * l2d);
    }

    f32x4 oA[4] = {}, oB[4] = {}, oC[4] = {}, oD[4] = {};
    float lpA[4] = {}, lpB[4] = {}, lpC[4] = {}, lpD[4] = {};

    for (int c = wave; c < ncD; c += 4) {
        const int kb = c * 32;
        bf16x8 k00 = load_bf16x8(kh + (kb + 2 * ln) * DH + lg * 8);
        bf16x8 k01 = load_bf16x8(kh + (kb + 2 * ln) * DH + 32 + lg * 8);
        bf16x8 k10 = load_bf16x8(kh + (kb + 2 * ln + 1) * DH + lg * 8);
        bf16x8 k11 = load_bf16x8(kh + (kb + 2 * ln + 1) * DH + 32 + lg * 8);
        bf16x8 j0 = (lane < 16) ? load_bf16x8(j8 + (size_t)(kb + 2 * ln) * 8) : zf;
        bf16x8 j1 = (lane < 16) ? load_bf16x8(j8 + (size_t)(kb + 2 * ln + 1) * 8) : zf;
        bf16x8 vf0 = load_bf16x8(vh + (size_t)(ln) * T_DIM + kb + lg * 8);
        bf16x8 vf1 = load_bf16x8(vh + (size_t)(16 + ln) * T_DIM + kb + lg * 8);
        bf16x8 vf2 = load_bf16x8(vh + (size_t)(32 + ln) * T_DIM + kb + lg * 8);
        bf16x8 vf3 = load_bf16x8(vh + (size_t)(48 + ln) * T_DIM + kb + lg * 8);
        const bool doC = (c < ncC), doB = (c < ncB), doA = (c < ncA);

        QKSM(D);
        if (doC) QKSM(C);
        if (doB) QKSM(B);
        if (doA) QKSM(A);

        PVSTEP(D);
        if (doC) PVSTEP(C);
        if (doB) PVSTEP(B);
        if (doA) PVSTEP(A);
    }

#pragma unroll
    for (int r = 0; r < 4; ++r) {
#pragma unroll
        for (int off = 1; off < 16; off <<= 1) {
            lpA[r] += __shfl_xor(lpA[r], off, 16);
            lpB[r] += __shfl_xor(lpB[r], off, 16);
            lpC[r] += __shfl_xor(lpC[r], off, 16);
            lpD[r] += __shfl_xor(lpD[r], off, 16);
        }
    }

    const int row = threadIdx.x >> 4;
    const int c4 = (threadIdx.x & 15) * 4;

    WRITE_OUT(A);
    WRITE_OUT(B);
    WRITE_OUT(C);
    WRITE_OUT(D);
}

extern "C" void kernel_launch(void* const* d_in, const int* in_sizes, int n_in,
                              void* d_out, int out_size, void* d_ws, size_t ws_size,
                              hipStream_t stream)
{
    const float* x    = (const float*)d_in[0];
    const float* wqkv = (const float*)d_in[1];
    const float* bqkv = (const float*)d_in[2];
    const float* w1w  = (const float*)d_in[3];
    const float* w2w  = (const float*)d_in[4];
    const float* w1r  = (const float*)d_in[5];
    const float* w2r  = (const float*)d_in[6];
    const float* wout = (const float*)d_in[7];
    const float* bout = (const float*)d_in[8];
    const float* dlog = (const float*)d_in[9];
    const float* bsc  = (const float*)d_in[10];
    float* out = (float*)d_out;

    char* ws = (char*)d_ws;
    bhalf* qb    = (bhalf*)(ws);                 // [B,H,T,64] bf16   8388608 B
    bhalf* kbuf  = (bhalf*)(ws + 8388608);       // [B,H,T,64] bf16   8388608 B
    bhalf* vtb   = (bhalf*)(ws + 16777216);      // [B,H,64,T] bf16   8388608 B
    bhalf* r8    = (bhalf*)(ws + 25165824);      // [B,H,T,8]  bf16   1048576 B
    bhalf* j8    = (bhalf*)(ws + 26214400);      // [B,H,T,8]  bf16   1048576 B
    float* proj  = (float*)(ws + 27262976);      // [B*T,256]  f32    4194304 B
    bhalf* ao    = (bhalf*)(ws + 31457280);      // [B*T,1024] bf16   8388608 B
    bhalf* woutbf = (bhalf*)(ws + 39845888);     // [1024,1024] bf16  2097152 B

    bhalf* xbf  = (bhalf*)d_out;                      //  8388608 B
    bhalf* wcat = (bhalf*)((char*)d_out + 8388608);   //  6815744 B (3328x1024)

    cvt_all<<<4224, 256, 0, stream>>>(x, wqkv, w1w, w2w, w1r, w2r, wout, xbf, wcat, woutbf);
    qkv_lines_gemm128<<<dim3(32, 26), 256, 0, stream>>>(xbf, wcat, bqkv, qb, kbuf, vtb, proj);
    build_lines<<<256, 256, 0, stream>>>(proj, bsc, dlog, r8, j8);
    attn_kernel<<<1024, 256, 0, stream>>>(qb, kbuf, vtb, r8, j8, dlog, ao);
    out_gemm64<<<dim3(64, 16), 256, 0, stream>>>(ao, woutbf, bout, out);
}

// Round 8
// 258.092 us; speedup vs baseline: 1.1174x; 1.0292x over previous
//
#include <hip/hip_runtime.h>
#include <hip/hip_bf16.h>

using bhalf = __hip_bfloat16;
typedef __bf16 bf16x8 __attribute__((ext_vector_type(8)));
typedef __bf16 bf16x2 __attribute__((ext_vector_type(2)));
typedef float f32x4 __attribute__((ext_vector_type(4)));

#define B_DIM 2
#define T_DIM 2048
#define D_DIM 1024
#define H_DIM 16
#define DH 64

struct bh8 { bhalf v[8]; };
struct bh4 { bhalf v[4]; };

__device__ __forceinline__ bf16x8 load_bf16x8(const bhalf* p) {
    return __builtin_bit_cast(bf16x8, *(const uint4*)p);
}
__device__ __forceinline__ bf16x8 zero_bf16x8() {
    uint4 z; z.x = 0; z.y = 0; z.z = 0; z.w = 0;
    return __builtin_bit_cast(bf16x8, z);
}
__device__ __forceinline__ void stage8_cvt(bhalf* dst, const float* src) {
    float4 a = *(const float4*)src;
    float4 b = *(const float4*)(src + 4);
    bh8 t;
    t.v[0] = __float2bfloat16(a.x); t.v[1] = __float2bfloat16(a.y);
    t.v[2] = __float2bfloat16(a.z); t.v[3] = __float2bfloat16(a.w);
    t.v[4] = __float2bfloat16(b.x); t.v[5] = __float2bfloat16(b.y);
    t.v[6] = __float2bfloat16(b.z); t.v[7] = __float2bfloat16(b.w);
    *(uint4*)dst = __builtin_bit_cast(uint4, t);
}

// async 16B global -> LDS (wave-uniform LDS base + lane*16)
#define GLD16(gp, lp) __builtin_amdgcn_global_load_lds( \
    (const __attribute__((address_space(1))) void*)(gp), \
    (__attribute__((address_space(3))) void*)(lp), 16, 0, 0)

// Segment sizes (elements)
#define SX  4194304
#define SW  3145728
#define SL  65536
#define SO  1048576
__global__ __launch_bounds__(256) void cvt_all(
    const float* __restrict__ x, const float* __restrict__ wqkv,
    const float* __restrict__ w1w, const float* __restrict__ w2w,
    const float* __restrict__ w1r, const float* __restrict__ w2r,
    const float* __restrict__ wout,
    bhalf* __restrict__ xbf, bhalf* __restrict__ wcat, bhalf* __restrict__ woutbf)
{
    int i = (blockIdx.x * 256 + threadIdx.x) * 8;
    if (i < SX) { stage8_cvt(xbf + i, x + i); return; }
    i -= SX;
    if (i < SW) { stage8_cvt(wcat + i, wqkv + i); return; }
    i -= SW;
    if (i < SL) { stage8_cvt(wcat + SW + i, w1w + i); return; }
    i -= SL;
    if (i < SL) { stage8_cvt(wcat + SW + SL + i, w2w + i); return; }
    i -= SL;
    if (i < SL) { stage8_cvt(wcat + SW + 2 * SL + i, w1r + i); return; }
    i -= SL;
    if (i < SL) { stage8_cvt(wcat + SW + 3 * SL + i, w2r + i); return; }
    i -= SL;
    if (i < SO) { stage8_cvt(woutbf + i, wout + i); }
}

// ---------------- 128x128 tile GEMM: C = A(128xK) * B(128xK)^T ----------------
__device__ __forceinline__ void gemm128_mainloop(
    const bhalf* __restrict__ A, const bhalf* __restrict__ B, int K,
    bhalf* As, bhalf* Bs, f32x4 acc[4][4])
{
    const int tid = threadIdx.x;
    const int wave = tid >> 6, lane = tid & 63;
    const int ln = lane & 15, lg = lane >> 4;
    const int wr = (wave >> 1) * 64, wc = (wave & 1) * 64;
    const int lrow = lane >> 3;
    const int lcol = (lane & 7) * 8;

    for (int kt = 0; kt < K; kt += 64) {
        __syncthreads();
#pragma unroll
        for (int i = 0; i < 4; ++i) {
            int idx = __builtin_amdgcn_readfirstlane(wave * 4 + i);
            GLD16(A + (size_t)(idx * 8 + lrow) * K + kt + lcol, As + idx * 512);
            GLD16(B + (size_t)(idx * 8 + lrow) * K + kt + lcol, Bs + idx * 512);
        }
        __syncthreads();
#pragma unroll
        for (int ks = 0; ks < 2; ++ks) {
            bf16x8 af[4], bfr[4];
#pragma unroll
            for (int mt = 0; mt < 4; ++mt)
                af[mt] = load_bf16x8(As + (wr + mt * 16 + ln) * 64 + ks * 32 + lg * 8);
#pragma unroll
            for (int nt = 0; nt < 4; ++nt)
                bfr[nt] = load_bf16x8(Bs + (wc + nt * 16 + ln) * 64 + ks * 32 + lg * 8);
#pragma unroll
            for (int mt = 0; mt < 4; ++mt)
#pragma unroll
                for (int nt = 0; nt < 4; ++nt)
                    acc[mt][nt] = __builtin_amdgcn_mfma_f32_16x16x32_bf16(af[mt], bfr[nt], acc[mt][nt], 0, 0, 0);
        }
    }
}

// fused qkv + lines projection: B = [w_qkv(3072); w1w;w2w;w1r;w2r(256)] rows, N=3328
// Q is pre-scaled by 0.125*log2(e) so attn scores are already in log2 domain.
__global__ __launch_bounds__(256) void qkv_lines_gemm128(
    const bhalf* __restrict__ x, const bhalf* __restrict__ wcat, const float* __restrict__ bqkv,
    bhalf* __restrict__ qo, bhalf* __restrict__ ko, bhalf* __restrict__ vt,
    float* __restrict__ proj)
{
    __shared__ bhalf As[128 * 64];
    __shared__ bhalf Bs[128 * 64];
    f32x4 acc[4][4] = {};
    gemm128_mainloop(x + (size_t)blockIdx.x * 128 * D_DIM,
                     wcat + (size_t)blockIdx.y * 128 * D_DIM, D_DIM, As, Bs, acc);
    const int wave = threadIdx.x >> 6, lane = threadIdx.x & 63;
    const int ln = lane & 15, lg = lane >> 4;
    const int wr = (wave >> 1) * 64, wc = (wave & 1) * 64;
    const int trip = (blockIdx.y * 128) >> 10;   // uniform per block (128 | 1024)

    if (trip == 2) {
        // v^T: pack 4 consecutive-t values -> one 8B store per (mt,nt)
#pragma unroll
        for (int nt = 0; nt < 4; ++nt) {
            int n = blockIdx.y * 128 + wc + nt * 16 + ln;
            float bias = bqkv[n];
            int h = (n >> 6) & 15, d = n & 63;
#pragma unroll
            for (int mt = 0; mt < 4; ++mt) {
                int tok0 = blockIdx.x * 128 + wr + mt * 16 + lg * 4;
                int b = tok0 >> 11, t0 = tok0 & (T_DIM - 1);
                bh4 pk;
#pragma unroll
                for (int r = 0; r < 4; ++r)
                    pk.v[r] = __float2bfloat16(acc[mt][nt][r] + bias);
                *(uint2*)&vt[(((size_t)(b * H_DIM + h)) * DH + d) * T_DIM + t0] =
                    __builtin_bit_cast(uint2, pk);
            }
        }
    } else {
#pragma unroll
        for (int nt = 0; nt < 4; ++nt) {
            int n = blockIdx.y * 128 + wc + nt * 16 + ln;
            int h = (n >> 6) & 15, d = n & 63;
            float bias = (trip < 3) ? bqkv[n] : 0.f;
#pragma unroll
            for (int mt = 0; mt < 4; ++mt)
#pragma unroll
                for (int r = 0; r < 4; ++r) {
                    int tok = blockIdx.x * 128 + wr + mt * 16 + lg * 4 + r;
                    int b = tok >> 11, t = tok & (T_DIM - 1);
                    float y = acc[mt][nt][r] + bias;
                    if (trip == 0) {
                        // 0.125 * log2(e)
                        qo[(((size_t)(b * H_DIM + h)) * T_DIM + t) * DH + d] = __float2bfloat16(y * 0.18033688f);
                    } else if (trip == 1) {
                        ko[(((size_t)(b * H_DIM + h)) * T_DIM + t) * DH + d] = __float2bfloat16(y);
                    } else {
                        proj[(size_t)tok * 256 + (n - 3072)] = y;
                    }
                }
        }
    }
}

// 64x64 bf16 GEMM with global_load_lds staging (out projection; 1024 blocks,
// 4 blocks/CU -- R0-proven; 128^2 variant's 1 block/CU was slower).
__global__ __launch_bounds__(256) void out_gemm64(
    const bhalf* __restrict__ a, const bhalf* __restrict__ w, const float* __restrict__ bo,
    float* __restrict__ out)
{
    __shared__ bhalf As[64 * 64];
    __shared__ bhalf Bs[64 * 64];
    const int tid = threadIdx.x;
    const int wave = tid >> 6, lane = tid & 63;
    const int ln = lane & 15, lg = lane >> 4;
    const int lrow = lane >> 3;
    const int lcol = (lane & 7) * 8;
    const bhalf* A = a + (size_t)blockIdx.x * 64 * D_DIM;
    const bhalf* B = w + (size_t)blockIdx.y * 64 * D_DIM;
    f32x4 acc[4] = {};

    for (int kt = 0; kt < D_DIM; kt += 64) {
        __syncthreads();
#pragma unroll
        for (int i = 0; i < 2; ++i) {
            int idx = __builtin_amdgcn_readfirstlane(wave * 2 + i);
            GLD16(A + (size_t)(idx * 8 + lrow) * D_DIM + kt + lcol, As + idx * 512);
            GLD16(B + (size_t)(idx * 8 + lrow) * D_DIM + kt + lcol, Bs + idx * 512);
        }
        __syncthreads();
#pragma unroll
        for (int ks = 0; ks < 2; ++ks) {
            bf16x8 af = load_bf16x8(As + (wave * 16 + ln) * 64 + ks * 32 + lg * 8);
#pragma unroll
            for (int nt = 0; nt < 4; ++nt) {
                bf16x8 bfr = load_bf16x8(Bs + (nt * 16 + ln) * 64 + ks * 32 + lg * 8);
                acc[nt] = __builtin_amdgcn_mfma_f32_16x16x32_bf16(af, bfr, acc[nt], 0, 0, 0);
            }
        }
    }
#pragma unroll
    for (int nt = 0; nt < 4; ++nt) {
        int n = blockIdx.y * 64 + nt * 16 + ln;
        float bias = bo[n];
#pragma unroll
        for (int r = 0; r < 4; ++r) {
            int tok = blockIdx.x * 64 + wave * 16 + lg * 4 + r;
            out[(size_t)tok * D_DIM + n] = acc[nt][r] + bias;
        }
    }
}

__global__ __launch_bounds__(256) void build_lines(
    const float* __restrict__ proj, const float* __restrict__ bias_scale,
    const float* __restrict__ decay_logits,
    bhalf* __restrict__ read8, bhalf* __restrict__ jw8)
{
    int id = blockIdx.x * 256 + threadIdx.x;
    int tok = id >> 4, h = id & 15;
    int b = tok >> 11, t = tok & (T_DIM - 1);
    const float* pr = proj + (size_t)tok * 256;

    float p1[4], p2[4], r1[4], r2[4];
#pragma unroll
    for (int i = 0; i < 4; ++i) {
        p1[i] = (t > 0) ? pr[-256 + h * 4 + i] : 0.f;
        p2[i] = pr[64 + h * 4 + i];
        r1[i] = pr[128 + h * 4 + i];
        r2[i] = pr[192 + h * 4 + i];
    }
    float Lw[6], Lr[6];
    {
        Lw[0] = p1[0] * p2[1] - p1[1] * p2[0];
        Lw[1] = p1[0] * p2[2] - p1[2] * p2[0];
        Lw[2] = p1[0] * p2[3] - p1[3] * p2[0];
        Lw[3] = p1[1] * p2[2] - p1[2] * p2[1];
        Lw[4] = p1[1] * p2[3] - p1[3] * p2[1];
        Lw[5] = p1[2] * p2[3] - p1[3] * p2[2];
        float n2 = 0.f;
#pragma unroll
        for (int j = 0; j < 6; ++j) n2 += Lw[j] * Lw[j];
        float inv = 1.f / fmaxf(sqrtf(n2), 1e-12f);
#pragma unroll
        for (int j = 0; j < 6; ++j) Lw[j] *= inv;
    }
    {
        Lr[0] = r1[0] * r2[1] - r1[1] * r2[0];
        Lr[1] = r1[0] * r2[2] - r1[2] * r2[0];
        Lr[2] = r1[0] * r2[3] - r1[3] * r2[0];
        Lr[3] = r1[1] * r2[2] - r1[2] * r2[1];
        Lr[4] = r1[1] * r2[3] - r1[3] * r2[1];
        Lr[5] = r1[2] * r2[3] - r1[3] * r2[2];
        float n2 = 0.f;
#pragma unroll
        for (int j = 0; j < 6; ++j) n2 += Lr[j] * Lr[j];
        float inv = 1.f / fmaxf(sqrtf(n2), 1e-12f);
#pragma unroll
        for (int j = 0; j < 6; ++j) Lr[j] *= inv;
    }
    float decay = 1.f / (1.f + __expf(-decay_logits[h]));
    float l2d = log2f(decay);
    float bs = bias_scale[h] * exp2f(-(float)t * l2d);
    size_t base = (((size_t)(b * H_DIM + h)) * T_DIM + t) * 8;
    read8[base + 0] = __float2bfloat16(Lr[0]);
    read8[base + 1] = __float2bfloat16(Lr[1]);
    read8[base + 2] = __float2bfloat16(Lr[2]);
    read8[base + 3] = __float2bfloat16(Lr[3]);
    read8[base + 4] = __float2bfloat16(Lr[4]);
    read8[base + 5] = __float2bfloat16(Lr[5]);
    read8[base + 6] = __float2bfloat16(0.f);
    read8[base + 7] = __float2bfloat16(0.f);
    jw8[base + 0] = __float2bfloat16(Lw[5] * bs);
    jw8[base + 1] = __float2bfloat16(-Lw[4] * bs);
    jw8[base + 2] = __float2bfloat16(Lw[3] * bs);
    jw8[base + 3] = __float2bfloat16(Lw[2] * bs);
    jw8[base + 4] = __float2bfloat16(-Lw[1] * bs);
    jw8[base + 5] = __float2bfloat16(Lw[0] * bs);
    jw8[base + 6] = __float2bfloat16(0.f);
    jw8[base + 7] = __float2bfloat16(0.f);
}

// softmax tile step for a 32-col half: scores -> P (packed bf16x2 stores).
// P-LDS pitch is 72 bf16 (64 cols + 8 pad). kb passed is the half's base col.
template<bool DIAG>
__device__ __forceinline__ void tile_step(
    const f32x4& z0, const f32x4& z1, const f32x4& i0, const f32x4& i1,
    int rq, int kb, const float* aq, int lg, int ln, bhalf* pl, float* lp)
{
#pragma unroll
    for (int r = 0; r < 4; ++r) {
        float p0, p1;
        if (DIAG) {
            int diff0 = rq + lg * 4 + r - (kb + 2 * ln);
            float s0 = z0[r] + ((diff0 > 0) ? i0[r] * aq[r] : 0.f);
            p0 = (diff0 < 0) ? 0.f : __builtin_amdgcn_exp2f(s0);
            int diff1 = diff0 - 1;
            float s1 = z1[r] + ((diff1 > 0) ? i1[r] * aq[r] : 0.f);
            p1 = (diff1 < 0) ? 0.f : __builtin_amdgcn_exp2f(s1);
        } else {
            p0 = __builtin_amdgcn_exp2f(fmaf(i0[r], aq[r], z0[r]));
            p1 = __builtin_amdgcn_exp2f(fmaf(i1[r], aq[r], z1[r]));
        }
        bf16x2 h2;
        h2.x = (__bf16)p0;
        h2.y = (__bf16)p1;
        *(unsigned int*)&pl[(lg * 4 + r) * 72 + 2 * ln] = __builtin_bit_cast(unsigned int, h2);
        lp[r] += p0 + p1;
    }
}

// Attention: 4 Q-tiles per block (R7 win: 112->100us) + 64-wide k-tiles (R8).
// R8 rationale: counters show per-iteration serial latency dominates (all
// pipes <27% busy); R7 proved fatter iterations win. Doubling the k-width
// halves the number of serial chains per unit work. 20 loads/iter, P-LDS
// pitch 72, LDS 36864B (fits 4 blocks/CU). VGPR est <240 (tripwire:
// WRITE_SIZE must stay 8192KB).
// DIAG per 64-block (last iter of tile T): half0 DIAG iff (T&3)<2 (else
// fully-past-diag -> FULL); half1 always DIAG (degenerates to zeros when
// diag is in half0 -- diff<0 path).
#define MFMA_BF16 __builtin_amdgcn_mfma_f32_16x16x32_bf16

#define QKSM64(T) { \
    { f32x4 z0 = {}, z1 = {}, i0 = {}, i1 = {}; \
      z0 = MFMA_BF16(q##T##0, k00, z0, 0, 0, 0); \
      z0 = MFMA_BF16(q##T##1, k01, z0, 0, 0, 0); \
      i0 = MFMA_BF16(rf##T, j0, i0, 0, 0, 0); \
      z1 = MFMA_BF16(q##T##0, k10, z1, 0, 0, 0); \
      z1 = MFMA_BF16(q##T##1, k11, z1, 0, 0, 0); \
      i1 = MFMA_BF16(rf##T, j1, i1, 0, 0, 0); \
      if (c == nc##T - 1 && (t##T & 3) < 2) \
          tile_step<true >(z0, z1, i0, i1, rq##T, kb, aq##T, lg, ln, pl##T, lp##T); \
      else \
          tile_step<false>(z0, z1, i0, i1, rq##T, kb, aq##T, lg, ln, pl##T, lp##T); \
    } \
    { f32x4 z0 = {}, z1 = {}, i0 = {}, i1 = {}; \
      z0 = MFMA_BF16(q##T##0, k00b, z0, 0, 0, 0); \
      z0 = MFMA_BF16(q##T##1, k01b, z0, 0, 0, 0); \
      i0 = MFMA_BF16(rf##T, j0b, i0, 0, 0, 0); \
      z1 = MFMA_BF16(q##T##0, k10b, z1, 0, 0, 0); \
      z1 = MFMA_BF16(q##T##1, k11b, z1, 0, 0, 0); \
      i1 = MFMA_BF16(rf##T, j1b, i1, 0, 0, 0); \
      if (c == nc##T - 1) \
          tile_step<true >(z0, z1, i0, i1, rq##T, kb + 32, aq##T, lg, ln, pl##T + 32, lp##T); \
      else \
          tile_step<false>(z0, z1, i0, i1, rq##T, kb + 32, aq##T, lg, ln, pl##T + 32, lp##T); \
    } }

#define PVSTEP64(T) { \
    bf16x8 pf0 = load_bf16x8(pl##T + ln * 72 + lg * 8); \
    bf16x8 pf1 = load_bf16x8(pl##T + ln * 72 + 32 + lg * 8); \
    o##T[0] = MFMA_BF16(pf0, vf0, o##T[0], 0, 0, 0); \
    o##T[1] = MFMA_BF16(pf0, vf1, o##T[1], 0, 0, 0); \
    o##T[2] = MFMA_BF16(pf0, vf2, o##T[2], 0, 0, 0); \
    o##T[3] = MFMA_BF16(pf0, vf3, o##T[3], 0, 0, 0); \
    o##T[0] = MFMA_BF16(pf1, vf4, o##T[0], 0, 0, 0); \
    o##T[1] = MFMA_BF16(pf1, vf5, o##T[1], 0, 0, 0); \
    o##T[2] = MFMA_BF16(pf1, vf6, o##T[2], 0, 0, 0); \
    o##T[3] = MFMA_BF16(pf1, vf7, o##T[3], 0, 0, 0); }

#define WRITE_OUT(T) { \
    __syncthreads(); \
    _Pragma("unroll") \
    for (int r = 0; r < 4; ++r) { \
        if (ln == 0) sm[wave * 1088 + (lg * 4 + r) * 68 + 64] = lp##T[r]; \
        _Pragma("unroll") \
        for (int nt = 0; nt < 4; ++nt) \
            sm[wave * 1088 + (lg * 4 + r) * 68 + nt * 16 + ln] = o##T[nt][r]; \
    } \
    __syncthreads(); \
    { \
        float l = 0.f; \
        _Pragma("unroll") \
        for (int w = 0; w < 4; ++w) l += sm[w * 1088 + row * 68 + 64]; \
        float4 acc = {0.f, 0.f, 0.f, 0.f}; \
        _Pragma("unroll") \
        for (int w = 0; w < 4; ++w) { \
            float4 t = *(const float4*)&sm[w * 1088 + row * 68 + c4]; \
            acc.x += t.x; acc.y += t.y; acc.z += t.z; acc.w += t.w; \
        } \
        float invl = 1.f / l; \
        bh4 pk; \
        pk.v[0] = __float2bfloat16(acc.x * invl); \
        pk.v[1] = __float2bfloat16(acc.y * invl); \
        pk.v[2] = __float2bfloat16(acc.z * invl); \
        pk.v[3] = __float2bfloat16(acc.w * invl); \
        size_t tok = (size_t)b * T_DIM + rq##T + row; \
        *(uint2*)&attn_out[tok * D_DIM + h * DH + c4] = __builtin_bit_cast(uint2, pk); \
    } }

__global__ __launch_bounds__(256) void attn_kernel(
    const bhalf* __restrict__ q, const bhalf* __restrict__ k, const bhalf* __restrict__ vt,
    const bhalf* __restrict__ read8, const bhalf* __restrict__ jw8,
    const float* __restrict__ decay_logits, bhalf* __restrict__ attn_out)
{
    __shared__ float sm[9216];   // 36864 B: 4 P buffers (pitch 72); epilogue reuses
    const int wave = threadIdx.x >> 6, lane = threadIdx.x & 63;
    const int ln = lane & 15, lg = lane >> 4;
    const int bx = blockIdx.x;               // 0..1023
    const int xcd = bx & 7;
    const int slot = bx >> 3;                // 0..127
    const int hbid = xcd * 4 + (slot >> 5);  // 0..31
    const int h = hbid & 15, b = hbid >> 4;
    const int j = slot & 31;
    // four Q-tiles (16 rows each), constant total work per block
    const int tA = j, tB = 63 - j, tC = 64 + j, tD = 127 - j;
    const int rqA = tA * 16, rqB = tB * 16, rqC = tC * 16, rqD = tD * 16;
    // 64-wide k iterations per tile
    const int ncA = (tA >> 2) + 1, ncB = (tB >> 2) + 1;
    const int ncC = (tC >> 2) + 1, ncD = (tD >> 2) + 1;
    const size_t hb = (size_t)(b * H_DIM + h);
    const bhalf* qh = q + hb * T_DIM * DH;
    const bhalf* kh = k + hb * T_DIM * DH;
    const bhalf* vh = vt + hb * DH * T_DIM;
    const bhalf* r8 = read8 + hb * T_DIM * 8;
    const bhalf* j8 = jw8 + hb * T_DIM * 8;

    bhalf* plA = (bhalf*)sm + 0 * 4608 + wave * 1152;   // 16 rows x 72
    bhalf* plB = (bhalf*)sm + 1 * 4608 + wave * 1152;
    bhalf* plC = (bhalf*)sm + 2 * 4608 + wave * 1152;
    bhalf* plD = (bhalf*)sm + 3 * 4608 + wave * 1152;

    bf16x8 zf = zero_bf16x8();
    bf16x8 qA0 = load_bf16x8(qh + (rqA + ln) * DH + lg * 8);
    bf16x8 qA1 = load_bf16x8(qh + (rqA + ln) * DH + 32 + lg * 8);
    bf16x8 qB0 = load_bf16x8(qh + (rqB + ln) * DH + lg * 8);
    bf16x8 qB1 = load_bf16x8(qh + (rqB + ln) * DH + 32 + lg * 8);
    bf16x8 qC0 = load_bf16x8(qh + (rqC + ln) * DH + lg * 8);
    bf16x8 qC1 = load_bf16x8(qh + (rqC + ln) * DH + 32 + lg * 8);
    bf16x8 qD0 = load_bf16x8(qh + (rqD + ln) * DH + lg * 8);
    bf16x8 qD1 = load_bf16x8(qh + (rqD + ln) * DH + 32 + lg * 8);
    bf16x8 rfA = (lane < 16) ? load_bf16x8(r8 + (size_t)(rqA + ln) * 8) : zf;
    bf16x8 rfB = (lane < 16) ? load_bf16x8(r8 + (size_t)(rqB + ln) * 8) : zf;
    bf16x8 rfC = (lane < 16) ? load_bf16x8(r8 + (size_t)(rqC + ln) * 8) : zf;
    bf16x8 rfD = (lane < 16) ? load_bf16x8(r8 + (size_t)(rqD + ln) * 8) : zf;

    float decay = 1.f / (1.f + __expf(-decay_logits[h]));
    float l2d = log2f(decay);
    const float LOG2E = 1.44269504f;
    float aqA[4], aqB[4], aqC[4], aqD[4];
#pragma unroll
    for (int r = 0; r < 4; ++r) {
        aqA[r] = LOG2E * __builtin_amdgcn_exp2f((float)(rqA + lg * 4 + r) * l2d);
        aqB[r] = LOG2E * __builtin_amdgcn_exp2f((float)(rqB + lg * 4 + r) * l2d);
        aqC[r] = LOG2E * __builtin_amdgcn_exp2f((float)(rqC + lg * 4 + r) * l2d);
        aqD[r] = LOG2E * __builtin_amdgcn_exp2f((float)(rqD + lg * 4 + r) * l2d);
    }

    f32x4 oA[4] = {}, oB[4] = {}, oC[4] = {}, oD[4] = {};
    float lpA[4] = {}, lpB[4] = {}, lpC[4] = {}, lpD[4] = {};

    for (int c = wave; c < ncD; c += 4) {
        const int kb = c * 64;
        // half0 (cols kb..kb+31)
        bf16x8 k00 = load_bf16x8(kh + (kb + 2 * ln) * DH + lg * 8);
        bf16x8 k01 = load_bf16x8(kh + (kb + 2 * ln) * DH + 32 + lg * 8);
        bf16x8 k10 = load_bf16x8(kh + (kb + 2 * ln + 1) * DH + lg * 8);
        bf16x8 k11 = load_bf16x8(kh + (kb + 2 * ln + 1) * DH + 32 + lg * 8);
        bf16x8 j0 = (lane < 16) ? load_bf16x8(j8 + (size_t)(kb + 2 * ln) * 8) : zf;
        bf16x8 j1 = (lane < 16) ? load_bf16x8(j8 + (size_t)(kb + 2 * ln + 1) * 8) : zf;
        // half1 (cols kb+32..kb+63)
        bf16x8 k00b = load_bf16x8(kh + (kb + 32 + 2 * ln) * DH + lg * 8);
        bf16x8 k01b = load_bf16x8(kh + (kb + 32 + 2 * ln) * DH + 32 + lg * 8);
        bf16x8 k10b = load_bf16x8(kh + (kb + 32 + 2 * ln + 1) * DH + lg * 8);
        bf16x8 k11b = load_bf16x8(kh + (kb + 32 + 2 * ln + 1) * DH + 32 + lg * 8);
        bf16x8 j0b = (lane < 16) ? load_bf16x8(j8 + (size_t)(kb + 32 + 2 * ln) * 8) : zf;
        bf16x8 j1b = (lane < 16) ? load_bf16x8(j8 + (size_t)(kb + 32 + 2 * ln + 1) * 8) : zf;
        // V both halves
        bf16x8 vf0 = load_bf16x8(vh + (size_t)(ln) * T_DIM + kb + lg * 8);
        bf16x8 vf1 = load_bf16x8(vh + (size_t)(16 + ln) * T_DIM + kb + lg * 8);
        bf16x8 vf2 = load_bf16x8(vh + (size_t)(32 + ln) * T_DIM + kb + lg * 8);
        bf16x8 vf3 = load_bf16x8(vh + (size_t)(48 + ln) * T_DIM + kb + lg * 8);
        bf16x8 vf4 = load_bf16x8(vh + (size_t)(ln) * T_DIM + kb + 32 + lg * 8);
        bf16x8 vf5 = load_bf16x8(vh + (size_t)(16 + ln) * T_DIM + kb + 32 + lg * 8);
        bf16x8 vf6 = load_bf16x8(vh + (size_t)(32 + ln) * T_DIM + kb + 32 + lg * 8);
        bf16x8 vf7 = load_bf16x8(vh + (size_t)(48 + ln) * T_DIM + kb + 32 + lg * 8);
        const bool doC = (c < ncC), doB = (c < ncB), doA = (c < ncA);

        QKSM64(D);
        if (doC) QKSM64(C);
        if (doB) QKSM64(B);
        if (doA) QKSM64(A);

        PVSTEP64(D);
        if (doC) PVSTEP64(C);
        if (doB) PVSTEP64(B);
        if (doA) PVSTEP64(A);
    }

#pragma unroll
    for (int r = 0; r < 4; ++r) {
#pragma unroll
        for (int off = 1; off < 16; off <<= 1) {
            lpA[r] += __shfl_xor(lpA[r], off, 16);
            lpB[r] += __shfl_xor(lpB[r], off, 16);
            lpC[r] += __shfl_xor(lpC[r], off, 16);
            lpD[r] += __shfl_xor(lpD[r], off, 16);
        }
    }

    const int row = threadIdx.x >> 4;
    const int c4 = (threadIdx.x & 15) * 4;

    WRITE_OUT(A);
    WRITE_OUT(B);
    WRITE_OUT(C);
    WRITE_OUT(D);
}

extern "C" void kernel_launch(void* const* d_in, const int* in_sizes, int n_in,
                              void* d_out, int out_size, void* d_ws, size_t ws_size,
                              hipStream_t stream)
{
    const float* x    = (const float*)d_in[0];
    const float* wqkv = (const float*)d_in[1];
    const float* bqkv = (const float*)d_in[2];
    const float* w1w  = (const float*)d_in[3];
    const float* w2w  = (const float*)d_in[4];
    const float* w1r  = (const float*)d_in[5];
    const float* w2r  = (const float*)d_in[6];
    const float* wout = (const float*)d_in[7];
    const float* bout = (const float*)d_in[8];
    const float* dlog = (const float*)d_in[9];
    const float* bsc  = (const float*)d_in[10];
    float* out = (float*)d_out;

    char* ws = (char*)d_ws;
    bhalf* qb    = (bhalf*)(ws);                 // [B,H,T,64] bf16   8388608 B
    bhalf* kbuf  = (bhalf*)(ws + 8388608);       // [B,H,T,64] bf16   8388608 B
    bhalf* vtb   = (bhalf*)(ws + 16777216);      // [B,H,64,T] bf16   8388608 B
    bhalf* r8    = (bhalf*)(ws + 25165824);      // [B,H,T,8]  bf16   1048576 B
    bhalf* j8    = (bhalf*)(ws + 26214400);      // [B,H,T,8]  bf16   1048576 B
    float* proj  = (float*)(ws + 27262976);      // [B*T,256]  f32    4194304 B
    bhalf* ao    = (bhalf*)(ws + 31457280);      // [B*T,1024] bf16   8388608 B
    bhalf* woutbf = (bhalf*)(ws + 39845888);     // [1024,1024] bf16  2097152 B

    bhalf* xbf  = (bhalf*)d_out;                      //  8388608 B
    bhalf* wcat = (bhalf*)((char*)d_out + 8388608);   //  6815744 B (3328x1024)

    cvt_all<<<4224, 256, 0, stream>>>(x, wqkv, w1w, w2w, w1r, w2r, wout, xbf, wcat, woutbf);
    qkv_lines_gemm128<<<dim3(32, 26), 256, 0, stream>>>(xbf, wcat, bqkv, qb, kbuf, vtb, proj);
    build_lines<<<256, 256, 0, stream>>>(proj, bsc, dlog, r8, j8);
    attn_kernel<<<1024, 256, 0, stream>>>(qb, kbuf, vtb, r8, j8, dlog, ao);
    out_gemm64<<<dim3(64, 16), 256, 0, stream>>>(ao, woutbf, bout, out);
}

// Round 9
// 256.565 us; speedup vs baseline: 1.1240x; 1.0059x over previous
//
#include <hip/hip_runtime.h>
#include <hip/hip_bf16.h>

using bhalf = __hip_bfloat16;
typedef __bf16 bf16x8 __attribute__((ext_vector_type(8)));
typedef __bf16 bf16x2 __attribute__((ext_vector_type(2)));
typedef float f32x4 __attribute__((ext_vector_type(4)));

#define B_DIM 2
#define T_DIM 2048
#define D_DIM 1024
#define H_DIM 16
#define DH 64

struct bh8 { bhalf v[8]; };
struct bh4 { bhalf v[4]; };

__device__ __forceinline__ bf16x8 load_bf16x8(const bhalf* p) {
    return __builtin_bit_cast(bf16x8, *(const uint4*)p);
}
__device__ __forceinline__ bf16x8 zero_bf16x8() {
    uint4 z; z.x = 0; z.y = 0; z.z = 0; z.w = 0;
    return __builtin_bit_cast(bf16x8, z);
}
__device__ __forceinline__ void stage8_cvt(bhalf* dst, const float* src) {
    float4 a = *(const float4*)src;
    float4 b = *(const float4*)(src + 4);
    bh8 t;
    t.v[0] = __float2bfloat16(a.x); t.v[1] = __float2bfloat16(a.y);
    t.v[2] = __float2bfloat16(a.z); t.v[3] = __float2bfloat16(a.w);
    t.v[4] = __float2bfloat16(b.x); t.v[5] = __float2bfloat16(b.y);
    t.v[6] = __float2bfloat16(b.z); t.v[7] = __float2bfloat16(b.w);
    *(uint4*)dst = __builtin_bit_cast(uint4, t);
}

// async 16B global -> LDS (wave-uniform LDS base + lane*16)
#define GLD16(gp, lp) __builtin_amdgcn_global_load_lds( \
    (const __attribute__((address_space(1))) void*)(gp), \
    (__attribute__((address_space(3))) void*)(lp), 16, 0, 0)

// Segment sizes (elements)
#define SX  4194304
#define SW  3145728
#define SL  65536
#define SO  1048576
__global__ __launch_bounds__(256) void cvt_all(
    const float* __restrict__ x, const float* __restrict__ wqkv,
    const float* __restrict__ w1w, const float* __restrict__ w2w,
    const float* __restrict__ w1r, const float* __restrict__ w2r,
    const float* __restrict__ wout,
    bhalf* __restrict__ xbf, bhalf* __restrict__ wcat, bhalf* __restrict__ woutbf)
{
    int i = (blockIdx.x * 256 + threadIdx.x) * 8;
    if (i < SX) { stage8_cvt(xbf + i, x + i); return; }
    i -= SX;
    if (i < SW) { stage8_cvt(wcat + i, wqkv + i); return; }
    i -= SW;
    if (i < SL) { stage8_cvt(wcat + SW + i, w1w + i); return; }
    i -= SL;
    if (i < SL) { stage8_cvt(wcat + SW + SL + i, w2w + i); return; }
    i -= SL;
    if (i < SL) { stage8_cvt(wcat + SW + 2 * SL + i, w1r + i); return; }
    i -= SL;
    if (i < SL) { stage8_cvt(wcat + SW + 3 * SL + i, w2r + i); return; }
    i -= SL;
    if (i < SO) { stage8_cvt(woutbf + i, wout + i); }
}

// ---------------- 128x128 tile GEMM: C = A(128xK) * B(128xK)^T ----------------
__device__ __forceinline__ void gemm128_mainloop(
    const bhalf* __restrict__ A, const bhalf* __restrict__ B, int K,
    bhalf* As, bhalf* Bs, f32x4 acc[4][4])
{
    const int tid = threadIdx.x;
    const int wave = tid >> 6, lane = tid & 63;
    const int ln = lane & 15, lg = lane >> 4;
    const int wr = (wave >> 1) * 64, wc = (wave & 1) * 64;
    const int lrow = lane >> 3;
    const int lcol = (lane & 7) * 8;

    for (int kt = 0; kt < K; kt += 64) {
        __syncthreads();
#pragma unroll
        for (int i = 0; i < 4; ++i) {
            int idx = __builtin_amdgcn_readfirstlane(wave * 4 + i);
            GLD16(A + (size_t)(idx * 8 + lrow) * K + kt + lcol, As + idx * 512);
            GLD16(B + (size_t)(idx * 8 + lrow) * K + kt + lcol, Bs + idx * 512);
        }
        __syncthreads();
#pragma unroll
        for (int ks = 0; ks < 2; ++ks) {
            bf16x8 af[4], bfr[4];
#pragma unroll
            for (int mt = 0; mt < 4; ++mt)
                af[mt] = load_bf16x8(As + (wr + mt * 16 + ln) * 64 + ks * 32 + lg * 8);
#pragma unroll
            for (int nt = 0; nt < 4; ++nt)
                bfr[nt] = load_bf16x8(Bs + (wc + nt * 16 + ln) * 64 + ks * 32 + lg * 8);
#pragma unroll
            for (int mt = 0; mt < 4; ++mt)
#pragma unroll
                for (int nt = 0; nt < 4; ++nt)
                    acc[mt][nt] = __builtin_amdgcn_mfma_f32_16x16x32_bf16(af[mt], bfr[nt], acc[mt][nt], 0, 0, 0);
        }
    }
}

// fused qkv + lines projection: B = [w_qkv(3072); w1w;w2w;w1r;w2r(256)] rows, N=3328
// Q is pre-scaled by 0.125*log2(e) so attn scores are already in log2 domain.
__global__ __launch_bounds__(256) void qkv_lines_gemm128(
    const bhalf* __restrict__ x, const bhalf* __restrict__ wcat, const float* __restrict__ bqkv,
    bhalf* __restrict__ qo, bhalf* __restrict__ ko, bhalf* __restrict__ vt,
    float* __restrict__ proj)
{
    __shared__ bhalf As[128 * 64];
    __shared__ bhalf Bs[128 * 64];
    f32x4 acc[4][4] = {};
    gemm128_mainloop(x + (size_t)blockIdx.x * 128 * D_DIM,
                     wcat + (size_t)blockIdx.y * 128 * D_DIM, D_DIM, As, Bs, acc);
    const int wave = threadIdx.x >> 6, lane = threadIdx.x & 63;
    const int ln = lane & 15, lg = lane >> 4;
    const int wr = (wave >> 1) * 64, wc = (wave & 1) * 64;
    const int trip = (blockIdx.y * 128) >> 10;   // uniform per block (128 | 1024)

    if (trip == 2) {
        // v^T: pack 4 consecutive-t values -> one 8B store per (mt,nt)
#pragma unroll
        for (int nt = 0; nt < 4; ++nt) {
            int n = blockIdx.y * 128 + wc + nt * 16 + ln;
            float bias = bqkv[n];
            int h = (n >> 6) & 15, d = n & 63;
#pragma unroll
            for (int mt = 0; mt < 4; ++mt) {
                int tok0 = blockIdx.x * 128 + wr + mt * 16 + lg * 4;
                int b = tok0 >> 11, t0 = tok0 & (T_DIM - 1);
                bh4 pk;
#pragma unroll
                for (int r = 0; r < 4; ++r)
                    pk.v[r] = __float2bfloat16(acc[mt][nt][r] + bias);
                *(uint2*)&vt[(((size_t)(b * H_DIM + h)) * DH + d) * T_DIM + t0] =
                    __builtin_bit_cast(uint2, pk);
            }
        }
    } else {
#pragma unroll
        for (int nt = 0; nt < 4; ++nt) {
            int n = blockIdx.y * 128 + wc + nt * 16 + ln;
            int h = (n >> 6) & 15, d = n & 63;
            float bias = (trip < 3) ? bqkv[n] : 0.f;
#pragma unroll
            for (int mt = 0; mt < 4; ++mt)
#pragma unroll
                for (int r = 0; r < 4; ++r) {
                    int tok = blockIdx.x * 128 + wr + mt * 16 + lg * 4 + r;
                    int b = tok >> 11, t = tok & (T_DIM - 1);
                    float y = acc[mt][nt][r] + bias;
                    if (trip == 0) {
                        // 0.125 * log2(e)
                        qo[(((size_t)(b * H_DIM + h)) * T_DIM + t) * DH + d] = __float2bfloat16(y * 0.18033688f);
                    } else if (trip == 1) {
                        ko[(((size_t)(b * H_DIM + h)) * T_DIM + t) * DH + d] = __float2bfloat16(y);
                    } else {
                        proj[(size_t)tok * 256 + (n - 3072)] = y;
                    }
                }
        }
    }
}

// 64x64 bf16 GEMM with global_load_lds staging (out projection; 1024 blocks,
// 4 blocks/CU -- R0-proven; 128^2 variant's 1 block/CU was slower).
__global__ __launch_bounds__(256) void out_gemm64(
    const bhalf* __restrict__ a, const bhalf* __restrict__ w, const float* __restrict__ bo,
    float* __restrict__ out)
{
    __shared__ bhalf As[64 * 64];
    __shared__ bhalf Bs[64 * 64];
    const int tid = threadIdx.x;
    const int wave = tid >> 6, lane = tid & 63;
    const int ln = lane & 15, lg = lane >> 4;
    const int lrow = lane >> 3;
    const int lcol = (lane & 7) * 8;
    const bhalf* A = a + (size_t)blockIdx.x * 64 * D_DIM;
    const bhalf* B = w + (size_t)blockIdx.y * 64 * D_DIM;
    f32x4 acc[4] = {};

    for (int kt = 0; kt < D_DIM; kt += 64) {
        __syncthreads();
#pragma unroll
        for (int i = 0; i < 2; ++i) {
            int idx = __builtin_amdgcn_readfirstlane(wave * 2 + i);
            GLD16(A + (size_t)(idx * 8 + lrow) * D_DIM + kt + lcol, As + idx * 512);
            GLD16(B + (size_t)(idx * 8 + lrow) * D_DIM + kt + lcol, Bs + idx * 512);
        }
        __syncthreads();
#pragma unroll
        for (int ks = 0; ks < 2; ++ks) {
            bf16x8 af = load_bf16x8(As + (wave * 16 + ln) * 64 + ks * 32 + lg * 8);
#pragma unroll
            for (int nt = 0; nt < 4; ++nt) {
                bf16x8 bfr = load_bf16x8(Bs + (nt * 16 + ln) * 64 + ks * 32 + lg * 8);
                acc[nt] = __builtin_amdgcn_mfma_f32_16x16x32_bf16(af, bfr, acc[nt], 0, 0, 0);
            }
        }
    }
#pragma unroll
    for (int nt = 0; nt < 4; ++nt) {
        int n = blockIdx.y * 64 + nt * 16 + ln;
        float bias = bo[n];
#pragma unroll
        for (int r = 0; r < 4; ++r) {
            int tok = blockIdx.x * 64 + wave * 16 + lg * 4 + r;
            out[(size_t)tok * D_DIM + n] = acc[nt][r] + bias;
        }
    }
}

__global__ __launch_bounds__(256) void build_lines(
    const float* __restrict__ proj, const float* __restrict__ bias_scale,
    const float* __restrict__ decay_logits,
    bhalf* __restrict__ read8, bhalf* __restrict__ jw8)
{
    int id = blockIdx.x * 256 + threadIdx.x;
    int tok = id >> 4, h = id & 15;
    int b = tok >> 11, t = tok & (T_DIM - 1);
    const float* pr = proj + (size_t)tok * 256;

    float p1[4], p2[4], r1[4], r2[4];
#pragma unroll
    for (int i = 0; i < 4; ++i) {
        p1[i] = (t > 0) ? pr[-256 + h * 4 + i] : 0.f;
        p2[i] = pr[64 + h * 4 + i];
        r1[i] = pr[128 + h * 4 + i];
        r2[i] = pr[192 + h * 4 + i];
    }
    float Lw[6], Lr[6];
    {
        Lw[0] = p1[0] * p2[1] - p1[1] * p2[0];
        Lw[1] = p1[0] * p2[2] - p1[2] * p2[0];
        Lw[2] = p1[0] * p2[3] - p1[3] * p2[0];
        Lw[3] = p1[1] * p2[2] - p1[2] * p2[1];
        Lw[4] = p1[1] * p2[3] - p1[3] * p2[1];
        Lw[5] = p1[2] * p2[3] - p1[3] * p2[2];
        float n2 = 0.f;
#pragma unroll
        for (int j = 0; j < 6; ++j) n2 += Lw[j] * Lw[j];
        float inv = 1.f / fmaxf(sqrtf(n2), 1e-12f);
#pragma unroll
        for (int j = 0; j < 6; ++j) Lw[j] *= inv;
    }
    {
        Lr[0] = r1[0] * r2[1] - r1[1] * r2[0];
        Lr[1] = r1[0] * r2[2] - r1[2] * r2[0];
        Lr[2] = r1[0] * r2[3] - r1[3] * r2[0];
        Lr[3] = r1[1] * r2[2] - r1[2] * r2[1];
        Lr[4] = r1[1] * r2[3] - r1[3] * r2[1];
        Lr[5] = r1[2] * r2[3] - r1[3] * r2[2];
        float n2 = 0.f;
#pragma unroll
        for (int j = 0; j < 6; ++j) n2 += Lr[j] * Lr[j];
        float inv = 1.f / fmaxf(sqrtf(n2), 1e-12f);
#pragma unroll
        for (int j = 0; j < 6; ++j) Lr[j] *= inv;
    }
    float decay = 1.f / (1.f + __expf(-decay_logits[h]));
    float l2d = log2f(decay);
    float bs = bias_scale[h] * exp2f(-(float)t * l2d);
    size_t base = (((size_t)(b * H_DIM + h)) * T_DIM + t) * 8;
    read8[base + 0] = __float2bfloat16(Lr[0]);
    read8[base + 1] = __float2bfloat16(Lr[1]);
    read8[base + 2] = __float2bfloat16(Lr[2]);
    read8[base + 3] = __float2bfloat16(Lr[3]);
    read8[base + 4] = __float2bfloat16(Lr[4]);
    read8[base + 5] = __float2bfloat16(Lr[5]);
    read8[base + 6] = __float2bfloat16(0.f);
    read8[base + 7] = __float2bfloat16(0.f);
    jw8[base + 0] = __float2bfloat16(Lw[5] * bs);
    jw8[base + 1] = __float2bfloat16(-Lw[4] * bs);
    jw8[base + 2] = __float2bfloat16(Lw[3] * bs);
    jw8[base + 3] = __float2bfloat16(Lw[2] * bs);
    jw8[base + 4] = __float2bfloat16(-Lw[1] * bs);
    jw8[base + 5] = __float2bfloat16(Lw[0] * bs);
    jw8[base + 6] = __float2bfloat16(0.f);
    jw8[base + 7] = __float2bfloat16(0.f);
}

// Swapped-QK softmax step (R9): S computed as mfma(K,Q) so each lane holds
// the full P sub-row for q = rq+ln at k = kb+8*lg+{0..7} (evens in ze, odds
// in zo). In-lane exp2 + pack -> the PV A-fragment DIRECTLY (pf element
// 2r = even k, 2r+1 = odd k). No LDS bounce, no cross-lane movement.
// lp is a per-lane scalar (row sum for q=ln over this lane's k subset).
template<bool DIAG>
__device__ __forceinline__ bf16x8 tile_step_sw(
    const f32x4& ze, const f32x4& zo, const f32x4& ie, const f32x4& io,
    int qrow, int kb, int lg, float aq, float& lp)
{
    bf16x8 pf;
    float s = lp;
#pragma unroll
    for (int r = 0; r < 4; ++r) {
        float pe, po;
        if (DIAG) {
            int de = qrow - (kb + 8 * lg + 2 * r);
            float se = ze[r] + ((de > 0) ? ie[r] * aq : 0.f);
            pe = (de < 0) ? 0.f : __builtin_amdgcn_exp2f(se);
            int dd = de - 1;
            float so = zo[r] + ((dd > 0) ? io[r] * aq : 0.f);
            po = (dd < 0) ? 0.f : __builtin_amdgcn_exp2f(so);
        } else {
            pe = __builtin_amdgcn_exp2f(fmaf(ie[r], aq, ze[r]));
            po = __builtin_amdgcn_exp2f(fmaf(io[r], aq, zo[r]));
        }
        pf[2 * r]     = (__bf16)pe;
        pf[2 * r + 1] = (__bf16)po;
        s += pe + po;
    }
    lp = s;
    return pf;
}

// Attention: 4 Q-tiles/block (R7) + 64-wide k (R8) + swapped-QK in-register
// P (R9). The paired-k register layout makes mfma(K,Q)'s output land exactly
// as the PV A-fragment after in-lane softmax -- the LDS P-bounce (64 writes +
// 16 reads + lgkm serialization per iteration) is deleted. Same loads, same
// MFMA count, same output mapping; aq/lp become per-lane scalars.
// DIAG selection per 64-block unchanged: half0 DIAG iff (t&3)<2 on last
// iter (else FULL: all k strictly past); half1 DIAG on last iter (zeros
// itself when diagonal is in half0 via the de<0 path).
#define MFMA_BF16 __builtin_amdgcn_mfma_f32_16x16x32_bf16

#define QKSM64(T) { \
    const bool last##T = (c == nc##T - 1); \
    { f32x4 ze = {}, zo = {}, ie = {}, io = {}; \
      ze = MFMA_BF16(k00, q##T##0, ze, 0, 0, 0); \
      ze = MFMA_BF16(k01, q##T##1, ze, 0, 0, 0); \
      zo = MFMA_BF16(k10, q##T##0, zo, 0, 0, 0); \
      zo = MFMA_BF16(k11, q##T##1, zo, 0, 0, 0); \
      ie = MFMA_BF16(j0, rf##T, ie, 0, 0, 0); \
      io = MFMA_BF16(j1, rf##T, io, 0, 0, 0); \
      if (last##T && (t##T & 3) < 2) \
          pfa##T = tile_step_sw<true >(ze, zo, ie, io, qr##T, kb, lg, aq##T, lp##T); \
      else \
          pfa##T = tile_step_sw<false>(ze, zo, ie, io, qr##T, kb, lg, aq##T, lp##T); \
    } \
    { f32x4 ze = {}, zo = {}, ie = {}, io = {}; \
      ze = MFMA_BF16(k00b, q##T##0, ze, 0, 0, 0); \
      ze = MFMA_BF16(k01b, q##T##1, ze, 0, 0, 0); \
      zo = MFMA_BF16(k10b, q##T##0, zo, 0, 0, 0); \
      zo = MFMA_BF16(k11b, q##T##1, zo, 0, 0, 0); \
      ie = MFMA_BF16(j0b, rf##T, ie, 0, 0, 0); \
      io = MFMA_BF16(j1b, rf##T, io, 0, 0, 0); \
      if (last##T) \
          pfb##T = tile_step_sw<true >(ze, zo, ie, io, qr##T, kb + 32, lg, aq##T, lp##T); \
      else \
          pfb##T = tile_step_sw<false>(ze, zo, ie, io, qr##T, kb + 32, lg, aq##T, lp##T); \
    } }

#define PVSTEP64(T) { \
    o##T[0] = MFMA_BF16(pfa##T, vf0, o##T[0], 0, 0, 0); \
    o##T[1] = MFMA_BF16(pfa##T, vf1, o##T[1], 0, 0, 0); \
    o##T[2] = MFMA_BF16(pfa##T, vf2, o##T[2], 0, 0, 0); \
    o##T[3] = MFMA_BF16(pfa##T, vf3, o##T[3], 0, 0, 0); \
    o##T[0] = MFMA_BF16(pfb##T, vf4, o##T[0], 0, 0, 0); \
    o##T[1] = MFMA_BF16(pfb##T, vf5, o##T[1], 0, 0, 0); \
    o##T[2] = MFMA_BF16(pfb##T, vf6, o##T[2], 0, 0, 0); \
    o##T[3] = MFMA_BF16(pfb##T, vf7, o##T[3], 0, 0, 0); }

#define WRITE_OUT(T) { \
    __syncthreads(); \
    if (lg == 0) sm[wave * 1088 + ln * 68 + 64] = lp##T; \
    _Pragma("unroll") \
    for (int r = 0; r < 4; ++r) { \
        _Pragma("unroll") \
        for (int nt = 0; nt < 4; ++nt) \
            sm[wave * 1088 + (lg * 4 + r) * 68 + nt * 16 + ln] = o##T[nt][r]; \
    } \
    __syncthreads(); \
    { \
        float l = 0.f; \
        _Pragma("unroll") \
        for (int w = 0; w < 4; ++w) l += sm[w * 1088 + row * 68 + 64]; \
        float4 acc = {0.f, 0.f, 0.f, 0.f}; \
        _Pragma("unroll") \
        for (int w = 0; w < 4; ++w) { \
            float4 t = *(const float4*)&sm[w * 1088 + row * 68 + c4]; \
            acc.x += t.x; acc.y += t.y; acc.z += t.z; acc.w += t.w; \
        } \
        float invl = 1.f / l; \
        bh4 pk; \
        pk.v[0] = __float2bfloat16(acc.x * invl); \
        pk.v[1] = __float2bfloat16(acc.y * invl); \
        pk.v[2] = __float2bfloat16(acc.z * invl); \
        pk.v[3] = __float2bfloat16(acc.w * invl); \
        size_t tok = (size_t)b * T_DIM + rq##T + row; \
        *(uint2*)&attn_out[tok * D_DIM + h * DH + c4] = __builtin_bit_cast(uint2, pk); \
    } }

__global__ __launch_bounds__(256) void attn_kernel(
    const bhalf* __restrict__ q, const bhalf* __restrict__ k, const bhalf* __restrict__ vt,
    const bhalf* __restrict__ read8, const bhalf* __restrict__ jw8,
    const float* __restrict__ decay_logits, bhalf* __restrict__ attn_out)
{
    __shared__ float sm[4352];   // 17408 B: epilogue only (P-LDS deleted)
    const int wave = threadIdx.x >> 6, lane = threadIdx.x & 63;
    const int ln = lane & 15, lg = lane >> 4;
    const int bx = blockIdx.x;               // 0..1023
    const int xcd = bx & 7;
    const int slot = bx >> 3;                // 0..127
    const int hbid = xcd * 4 + (slot >> 5);  // 0..31
    const int h = hbid & 15, b = hbid >> 4;
    const int j = slot & 31;
    // four Q-tiles (16 rows each), constant total work per block
    const int tA = j, tB = 63 - j, tC = 64 + j, tD = 127 - j;
    const int rqA = tA * 16, rqB = tB * 16, rqC = tC * 16, rqD = tD * 16;
    // 64-wide k iterations per tile
    const int ncA = (tA >> 2) + 1, ncB = (tB >> 2) + 1;
    const int ncC = (tC >> 2) + 1, ncD = (tD >> 2) + 1;
    const int qrA = rqA + ln, qrB = rqB + ln, qrC = rqC + ln, qrD = rqD + ln;
    const size_t hb = (size_t)(b * H_DIM + h);
    const bhalf* qh = q + hb * T_DIM * DH;
    const bhalf* kh = k + hb * T_DIM * DH;
    const bhalf* vh = vt + hb * DH * T_DIM;
    const bhalf* r8 = read8 + hb * T_DIM * 8;
    const bhalf* j8 = jw8 + hb * T_DIM * 8;

    bf16x8 zf = zero_bf16x8();
    bf16x8 qA0 = load_bf16x8(qh + (rqA + ln) * DH + lg * 8);
    bf16x8 qA1 = load_bf16x8(qh + (rqA + ln) * DH + 32 + lg * 8);
    bf16x8 qB0 = load_bf16x8(qh + (rqB + ln) * DH + lg * 8);
    bf16x8 qB1 = load_bf16x8(qh + (rqB + ln) * DH + 32 + lg * 8);
    bf16x8 qC0 = load_bf16x8(qh + (rqC + ln) * DH + lg * 8);
    bf16x8 qC1 = load_bf16x8(qh + (rqC + ln) * DH + 32 + lg * 8);
    bf16x8 qD0 = load_bf16x8(qh + (rqD + ln) * DH + lg * 8);
    bf16x8 qD1 = load_bf16x8(qh + (rqD + ln) * DH + 32 + lg * 8);
    bf16x8 rfA = (lane < 16) ? load_bf16x8(r8 + (size_t)(rqA + ln) * 8) : zf;
    bf16x8 rfB = (lane < 16) ? load_bf16x8(r8 + (size_t)(rqB + ln) * 8) : zf;
    bf16x8 rfC = (lane < 16) ? load_bf16x8(r8 + (size_t)(rqC + ln) * 8) : zf;
    bf16x8 rfD = (lane < 16) ? load_bf16x8(r8 + (size_t)(rqD + ln) * 8) : zf;

    float decay = 1.f / (1.f + __expf(-decay_logits[h]));
    float l2d = log2f(decay);
    const float LOG2E = 1.44269504f;
    float aqA = LOG2E * __builtin_amdgcn_exp2f((float)qrA * l2d);
    float aqB = LOG2E * __builtin_amdgcn_exp2f((float)qrB * l2d);
    float aqC = LOG2E * __builtin_amdgcn_exp2f((float)qrC * l2d);
    float aqD = LOG2E * __builtin_amdgcn_exp2f((float)qrD * l2d);

    f32x4 oA[4] = {}, oB[4] = {}, oC[4] = {}, oD[4] = {};
    float lpA = 0.f, lpB = 0.f, lpC = 0.f, lpD = 0.f;

    for (int c = wave; c < ncD; c += 4) {
        const int kb = c * 64;
        // half0 (k rows kb..kb+31): evens in k00/k01, odds in k10/k11
        bf16x8 k00 = load_bf16x8(kh + (kb + 2 * ln) * DH + lg * 8);
        bf16x8 k01 = load_bf16x8(kh + (kb + 2 * ln) * DH + 32 + lg * 8);
        bf16x8 k10 = load_bf16x8(kh + (kb + 2 * ln + 1) * DH + lg * 8);
        bf16x8 k11 = load_bf16x8(kh + (kb + 2 * ln + 1) * DH + 32 + lg * 8);
        bf16x8 j0 = (lane < 16) ? load_bf16x8(j8 + (size_t)(kb + 2 * ln) * 8) : zf;
        bf16x8 j1 = (lane < 16) ? load_bf16x8(j8 + (size_t)(kb + 2 * ln + 1) * 8) : zf;
        // half1 (k rows kb+32..kb+63)
        bf16x8 k00b = load_bf16x8(kh + (kb + 32 + 2 * ln) * DH + lg * 8);
        bf16x8 k01b = load_bf16x8(kh + (kb + 32 + 2 * ln) * DH + 32 + lg * 8);
        bf16x8 k10b = load_bf16x8(kh + (kb + 32 + 2 * ln + 1) * DH + lg * 8);
        bf16x8 k11b = load_bf16x8(kh + (kb + 32 + 2 * ln + 1) * DH + 32 + lg * 8);
        bf16x8 j0b = (lane < 16) ? load_bf16x8(j8 + (size_t)(kb + 32 + 2 * ln) * 8) : zf;
        bf16x8 j1b = (lane < 16) ? load_bf16x8(j8 + (size_t)(kb + 32 + 2 * ln + 1) * 8) : zf;
        // V both halves
        bf16x8 vf0 = load_bf16x8(vh + (size_t)(ln) * T_DIM + kb + lg * 8);
        bf16x8 vf1 = load_bf16x8(vh + (size_t)(16 + ln) * T_DIM + kb + lg * 8);
        bf16x8 vf2 = load_bf16x8(vh + (size_t)(32 + ln) * T_DIM + kb + lg * 8);
        bf16x8 vf3 = load_bf16x8(vh + (size_t)(48 + ln) * T_DIM + kb + lg * 8);
        bf16x8 vf4 = load_bf16x8(vh + (size_t)(ln) * T_DIM + kb + 32 + lg * 8);
        bf16x8 vf5 = load_bf16x8(vh + (size_t)(16 + ln) * T_DIM + kb + 32 + lg * 8);
        bf16x8 vf6 = load_bf16x8(vh + (size_t)(32 + ln) * T_DIM + kb + 32 + lg * 8);
        bf16x8 vf7 = load_bf16x8(vh + (size_t)(48 + ln) * T_DIM + kb + 32 + lg * 8);
        const bool doC = (c < ncC), doB = (c < ncB), doA = (c < ncA);

        bf16x8 pfaD, pfbD, pfaC, pfbC, pfaB, pfbB, pfaA, pfbA;
        QKSM64(D);
        if (doC) QKSM64(C);
        if (doB) QKSM64(B);
        if (doA) QKSM64(A);

        PVSTEP64(D);
        if (doC) PVSTEP64(C);
        if (doB) PVSTEP64(B);
        if (doA) PVSTEP64(A);
    }

    // finish row sums: lane's partial covers its lg-group's k subset
    lpA += __shfl_xor(lpA, 16); lpA += __shfl_xor(lpA, 32);
    lpB += __shfl_xor(lpB, 16); lpB += __shfl_xor(lpB, 32);
    lpC += __shfl_xor(lpC, 16); lpC += __shfl_xor(lpC, 32);
    lpD += __shfl_xor(lpD, 16); lpD += __shfl_xor(lpD, 32);

    const int row = threadIdx.x >> 4;
    const int c4 = (threadIdx.x & 15) * 4;

    WRITE_OUT(A);
    WRITE_OUT(B);
    WRITE_OUT(C);
    WRITE_OUT(D);
}

extern "C" void kernel_launch(void* const* d_in, const int* in_sizes, int n_in,
                              void* d_out, int out_size, void* d_ws, size_t ws_size,
                              hipStream_t stream)
{
    const float* x    = (const float*)d_in[0];
    const float* wqkv = (const float*)d_in[1];
    const float* bqkv = (const float*)d_in[2];
    const float* w1w  = (const float*)d_in[3];
    const float* w2w  = (const float*)d_in[4];
    const float* w1r  = (const float*)d_in[5];
    const float* w2r  = (const float*)d_in[6];
    const float* wout = (const float*)d_in[7];
    const float* bout = (const float*)d_in[8];
    const float* dlog = (const float*)d_in[9];
    const float* bsc  = (const float*)d_in[10];
    float* out = (float*)d_out;

    char* ws = (char*)d_ws;
    bhalf* qb    = (bhalf*)(ws);                 // [B,H,T,64] bf16   8388608 B
    bhalf* kbuf  = (bhalf*)(ws + 8388608);       // [B,H,T,64] bf16   8388608 B
    bhalf* vtb   = (bhalf*)(ws + 16777216);      // [B,H,64,T] bf16   8388608 B
    bhalf* r8    = (bhalf*)(ws + 25165824);      // [B,H,T,8]  bf16   1048576 B
    bhalf* j8    = (bhalf*)(ws + 26214400);      // [B,H,T,8]  bf16   1048576 B
    float* proj  = (float*)(ws + 27262976);      // [B*T,256]  f32    4194304 B
    bhalf* ao    = (bhalf*)(ws + 31457280);      // [B*T,1024] bf16   8388608 B
    bhalf* woutbf = (bhalf*)(ws + 39845888);     // [1024,1024] bf16  2097152 B

    bhalf* xbf  = (bhalf*)d_out;                      //  8388608 B
    bhalf* wcat = (bhalf*)((char*)d_out + 8388608);   //  6815744 B (3328x1024)

    cvt_all<<<4224, 256, 0, stream>>>(x, wqkv, w1w, w2w, w1r, w2r, wout, xbf, wcat, woutbf);
    qkv_lines_gemm128<<<dim3(32, 26), 256, 0, stream>>>(xbf, wcat, bqkv, qb, kbuf, vtb, proj);
    build_lines<<<256, 256, 0, stream>>>(proj, bsc, dlog, r8, j8);
    attn_kernel<<<1024, 256, 0, stream>>>(qb, kbuf, vtb, r8, j8, dlog, ao);
    out_gemm64<<<dim3(64, 16), 256, 0, stream>>>(ao, woutbf, bout, out);
}

// Round 10
// 252.240 us; speedup vs baseline: 1.1433x; 1.0171x over previous
//
#include <hip/hip_runtime.h>
#include <hip/hip_bf16.h>

using bhalf = __hip_bfloat16;
typedef __bf16 bf16x8 __attribute__((ext_vector_type(8)));
typedef __bf16 bf16x2 __attribute__((ext_vector_type(2)));
typedef float f32x4 __attribute__((ext_vector_type(4)));

#define B_DIM 2
#define T_DIM 2048
#define D_DIM 1024
#define H_DIM 16
#define DH 64

struct bh8 { bhalf v[8]; };
struct bh4 { bhalf v[4]; };

__device__ __forceinline__ bf16x8 load_bf16x8(const bhalf* p) {
    return __builtin_bit_cast(bf16x8, *(const uint4*)p);
}
__device__ __forceinline__ bf16x8 zero_bf16x8() {
    uint4 z; z.x = 0; z.y = 0; z.z = 0; z.w = 0;
    return __builtin_bit_cast(bf16x8, z);
}
__device__ __forceinline__ void stage8_cvt(bhalf* dst, const float* src) {
    float4 a = *(const float4*)src;
    float4 b = *(const float4*)(src + 4);
    bh8 t;
    t.v[0] = __float2bfloat16(a.x); t.v[1] = __float2bfloat16(a.y);
    t.v[2] = __float2bfloat16(a.z); t.v[3] = __float2bfloat16(a.w);
    t.v[4] = __float2bfloat16(b.x); t.v[5] = __float2bfloat16(b.y);
    t.v[6] = __float2bfloat16(b.z); t.v[7] = __float2bfloat16(b.w);
    *(uint4*)dst = __builtin_bit_cast(uint4, t);
}

// async 16B global -> LDS (wave-uniform LDS base + lane*16)
#define GLD16(gp, lp) __builtin_amdgcn_global_load_lds( \
    (const __attribute__((address_space(1))) void*)(gp), \
    (__attribute__((address_space(3))) void*)(lp), 16, 0, 0)

// Segment sizes (elements)
#define SX  4194304
#define SW  3145728
#define SL  65536
#define SO  1048576
__global__ __launch_bounds__(256) void cvt_all(
    const float* __restrict__ x, const float* __restrict__ wqkv,
    const float* __restrict__ w1w, const float* __restrict__ w2w,
    const float* __restrict__ w1r, const float* __restrict__ w2r,
    const float* __restrict__ wout,
    bhalf* __restrict__ xbf, bhalf* __restrict__ wcat, bhalf* __restrict__ woutbf)
{
    int i = (blockIdx.x * 256 + threadIdx.x) * 8;
    if (i < SX) { stage8_cvt(xbf + i, x + i); return; }
    i -= SX;
    if (i < SW) { stage8_cvt(wcat + i, wqkv + i); return; }
    i -= SW;
    if (i < SL) { stage8_cvt(wcat + SW + i, w1w + i); return; }
    i -= SL;
    if (i < SL) { stage8_cvt(wcat + SW + SL + i, w2w + i); return; }
    i -= SL;
    if (i < SL) { stage8_cvt(wcat + SW + 2 * SL + i, w1r + i); return; }
    i -= SL;
    if (i < SL) { stage8_cvt(wcat + SW + 3 * SL + i, w2r + i); return; }
    i -= SL;
    if (i < SO) { stage8_cvt(woutbf + i, wout + i); }
}

// ---------------- 128x128 tile GEMM: C = A(128xK) * B(128xK)^T ----------------
// C rows = A-tile rows (wr/mt/lg*4+r), C cols = B-tile rows (wc/nt/ln).
__device__ __forceinline__ void gemm128_mainloop(
    const bhalf* __restrict__ A, const bhalf* __restrict__ B, int K,
    bhalf* As, bhalf* Bs, f32x4 acc[4][4])
{
    const int tid = threadIdx.x;
    const int wave = tid >> 6, lane = tid & 63;
    const int ln = lane & 15, lg = lane >> 4;
    const int wr = (wave >> 1) * 64, wc = (wave & 1) * 64;
    const int lrow = lane >> 3;
    const int lcol = (lane & 7) * 8;

    for (int kt = 0; kt < K; kt += 64) {
        __syncthreads();
#pragma unroll
        for (int i = 0; i < 4; ++i) {
            int idx = __builtin_amdgcn_readfirstlane(wave * 4 + i);
            GLD16(A + (size_t)(idx * 8 + lrow) * K + kt + lcol, As + idx * 512);
            GLD16(B + (size_t)(idx * 8 + lrow) * K + kt + lcol, Bs + idx * 512);
        }
        __syncthreads();
#pragma unroll
        for (int ks = 0; ks < 2; ++ks) {
            bf16x8 af[4], bfr[4];
#pragma unroll
            for (int mt = 0; mt < 4; ++mt)
                af[mt] = load_bf16x8(As + (wr + mt * 16 + ln) * 64 + ks * 32 + lg * 8);
#pragma unroll
            for (int nt = 0; nt < 4; ++nt)
                bfr[nt] = load_bf16x8(Bs + (wc + nt * 16 + ln) * 64 + ks * 32 + lg * 8);
#pragma unroll
            for (int mt = 0; mt < 4; ++mt)
#pragma unroll
                for (int nt = 0; nt < 4; ++nt)
                    acc[mt][nt] = __builtin_amdgcn_mfma_f32_16x16x32_bf16(af[mt], bfr[nt], acc[mt][nt], 0, 0, 0);
        }
    }
}

// fused qkv + lines projection. R10: for trip 0/1/3 the mainloop runs with
// SWAPPED operands (A=weights, B=x) so C rows = features -> consecutive r =
// 4 consecutive d within one head -> vectorized 8B/16B stores (was 64 scalar
// 2B stores per thread, ~4K store-issue cycles/SIMD ~= the whole mainloop).
// trip 2 (v^T) keeps the original order (already packed over tokens).
// Q pre-scaled by 0.125*log2(e) (exp2-domain softmax).
__global__ __launch_bounds__(256) void qkv_lines_gemm128(
    const bhalf* __restrict__ x, const bhalf* __restrict__ wcat, const float* __restrict__ bqkv,
    bhalf* __restrict__ qo, bhalf* __restrict__ ko, bhalf* __restrict__ vt,
    float* __restrict__ proj)
{
    __shared__ bhalf As[128 * 64];
    __shared__ bhalf Bs[128 * 64];
    f32x4 acc[4][4] = {};
    const int wave = threadIdx.x >> 6, lane = threadIdx.x & 63;
    const int ln = lane & 15, lg = lane >> 4;
    const int wr = (wave >> 1) * 64, wc = (wave & 1) * 64;
    const int trip = (blockIdx.y * 128) >> 10;   // uniform per block

    if (trip == 2) {
        gemm128_mainloop(x + (size_t)blockIdx.x * 128 * D_DIM,
                         wcat + (size_t)blockIdx.y * 128 * D_DIM, D_DIM, As, Bs, acc);
        // v^T: pack 4 consecutive-t values -> one 8B store per (mt,nt)
#pragma unroll
        for (int nt = 0; nt < 4; ++nt) {
            int n = blockIdx.y * 128 + wc + nt * 16 + ln;
            float bias = bqkv[n];
            int h = (n >> 6) & 15, d = n & 63;
#pragma unroll
            for (int mt = 0; mt < 4; ++mt) {
                int tok0 = blockIdx.x * 128 + wr + mt * 16 + lg * 4;
                int b = tok0 >> 11, t0 = tok0 & (T_DIM - 1);
                bh4 pk;
#pragma unroll
                for (int r = 0; r < 4; ++r)
                    pk.v[r] = __float2bfloat16(acc[mt][nt][r] + bias);
                *(uint2*)&vt[(((size_t)(b * H_DIM + h)) * DH + d) * T_DIM + t0] =
                    __builtin_bit_cast(uint2, pk);
            }
        }
    } else {
        // swapped: C rows = weight features, C cols = tokens
        gemm128_mainloop(wcat + (size_t)blockIdx.y * 128 * D_DIM,
                         x + (size_t)blockIdx.x * 128 * D_DIM, D_DIM, As, Bs, acc);
#pragma unroll
        for (int mt = 0; mt < 4; ++mt) {
            int n0 = blockIdx.y * 128 + wr + mt * 16 + lg * 4;  // 4-aligned feature base
            int h = (n0 >> 6) & 15, d0 = n0 & 63;
            float4 b4 = {0.f, 0.f, 0.f, 0.f};
            if (trip < 3) b4 = *(const float4*)&bqkv[n0];
#pragma unroll
            for (int nt = 0; nt < 4; ++nt) {
                int tok = blockIdx.x * 128 + wc + nt * 16 + ln;
                int b = tok >> 11, t = tok & (T_DIM - 1);
                if (trip == 0) {
                    bh4 pk;   // 0.125 * log2(e) scale folded into Q
                    pk.v[0] = __float2bfloat16((acc[mt][nt][0] + b4.x) * 0.18033688f);
                    pk.v[1] = __float2bfloat16((acc[mt][nt][1] + b4.y) * 0.18033688f);
                    pk.v[2] = __float2bfloat16((acc[mt][nt][2] + b4.z) * 0.18033688f);
                    pk.v[3] = __float2bfloat16((acc[mt][nt][3] + b4.w) * 0.18033688f);
                    *(uint2*)&qo[(((size_t)(b * H_DIM + h)) * T_DIM + t) * DH + d0] =
                        __builtin_bit_cast(uint2, pk);
                } else if (trip == 1) {
                    bh4 pk;
                    pk.v[0] = __float2bfloat16(acc[mt][nt][0] + b4.x);
                    pk.v[1] = __float2bfloat16(acc[mt][nt][1] + b4.y);
                    pk.v[2] = __float2bfloat16(acc[mt][nt][2] + b4.z);
                    pk.v[3] = __float2bfloat16(acc[mt][nt][3] + b4.w);
                    *(uint2*)&ko[(((size_t)(b * H_DIM + h)) * T_DIM + t) * DH + d0] =
                        __builtin_bit_cast(uint2, pk);
                } else {  // trip == 3: proj, contiguous features -> float4
                    float4 v;
                    v.x = acc[mt][nt][0]; v.y = acc[mt][nt][1];
                    v.z = acc[mt][nt][2]; v.w = acc[mt][nt][3];
                    *(float4*)&proj[(size_t)tok * 256 + (n0 - 3072)] = v;
                }
            }
        }
    }
}

// 64x64 out projection, R10-swapped: A=w (features), B=attn rows (tokens).
// Consecutive r = 4 consecutive n -> one float4 store (was 16 scalar f32).
// Grid (64,16) = 1024 blocks = 4/CU (R0-proven occupancy).
__global__ __launch_bounds__(256) void out_gemm64(
    const bhalf* __restrict__ a, const bhalf* __restrict__ w, const float* __restrict__ bo,
    float* __restrict__ out)
{
    __shared__ bhalf As[64 * 64];
    __shared__ bhalf Bs[64 * 64];
    const int tid = threadIdx.x;
    const int wave = tid >> 6, lane = tid & 63;
    const int ln = lane & 15, lg = lane >> 4;
    const int lrow = lane >> 3;
    const int lcol = (lane & 7) * 8;
    const bhalf* A = w + (size_t)blockIdx.y * 64 * D_DIM;   // features
    const bhalf* B = a + (size_t)blockIdx.x * 64 * D_DIM;   // tokens
    f32x4 acc[4] = {};

    for (int kt = 0; kt < D_DIM; kt += 64) {
        __syncthreads();
#pragma unroll
        for (int i = 0; i < 2; ++i) {
            int idx = __builtin_amdgcn_readfirstlane(wave * 2 + i);
            GLD16(A + (size_t)(idx * 8 + lrow) * D_DIM + kt + lcol, As + idx * 512);
            GLD16(B + (size_t)(idx * 8 + lrow) * D_DIM + kt + lcol, Bs + idx * 512);
        }
        __syncthreads();
#pragma unroll
        for (int ks = 0; ks < 2; ++ks) {
            bf16x8 af = load_bf16x8(As + (wave * 16 + ln) * 64 + ks * 32 + lg * 8);
#pragma unroll
            for (int nt = 0; nt < 4; ++nt) {
                bf16x8 bfr = load_bf16x8(Bs + (nt * 16 + ln) * 64 + ks * 32 + lg * 8);
                acc[nt] = __builtin_amdgcn_mfma_f32_16x16x32_bf16(af, bfr, acc[nt], 0, 0, 0);
            }
        }
    }
    const int n0 = blockIdx.y * 64 + wave * 16 + lg * 4;   // 4-aligned feature base
    float4 b4 = *(const float4*)&bo[n0];
#pragma unroll
    for (int nt = 0; nt < 4; ++nt) {
        int tok = blockIdx.x * 64 + nt * 16 + ln;
        float4 v;
        v.x = acc[nt][0] + b4.x; v.y = acc[nt][1] + b4.y;
        v.z = acc[nt][2] + b4.z; v.w = acc[nt][3] + b4.w;
        *(float4*)&out[(size_t)tok * D_DIM + n0] = v;
    }
}

__global__ __launch_bounds__(256) void build_lines(
    const float* __restrict__ proj, const float* __restrict__ bias_scale,
    const float* __restrict__ decay_logits,
    bhalf* __restrict__ read8, bhalf* __restrict__ jw8)
{
    int id = blockIdx.x * 256 + threadIdx.x;
    int tok = id >> 4, h = id & 15;
    int b = tok >> 11, t = tok & (T_DIM - 1);
    const float* pr = proj + (size_t)tok * 256;

    float p1[4], p2[4], r1[4], r2[4];
#pragma unroll
    for (int i = 0; i < 4; ++i) {
        p1[i] = (t > 0) ? pr[-256 + h * 4 + i] : 0.f;
        p2[i] = pr[64 + h * 4 + i];
        r1[i] = pr[128 + h * 4 + i];
        r2[i] = pr[192 + h * 4 + i];
    }
    float Lw[6], Lr[6];
    {
        Lw[0] = p1[0] * p2[1] - p1[1] * p2[0];
        Lw[1] = p1[0] * p2[2] - p1[2] * p2[0];
        Lw[2] = p1[0] * p2[3] - p1[3] * p2[0];
        Lw[3] = p1[1] * p2[2] - p1[2] * p2[1];
        Lw[4] = p1[1] * p2[3] - p1[3] * p2[1];
        Lw[5] = p1[2] * p2[3] - p1[3] * p2[2];
        float n2 = 0.f;
#pragma unroll
        for (int j = 0; j < 6; ++j) n2 += Lw[j] * Lw[j];
        float inv = 1.f / fmaxf(sqrtf(n2), 1e-12f);
#pragma unroll
        for (int j = 0; j < 6; ++j) Lw[j] *= inv;
    }
    {
        Lr[0] = r1[0] * r2[1] - r1[1] * r2[0];
        Lr[1] = r1[0] * r2[2] - r1[2] * r2[0];
        Lr[2] = r1[0] * r2[3] - r1[3] * r2[0];
        Lr[3] = r1[1] * r2[2] - r1[2] * r2[1];
        Lr[4] = r1[1] * r2[3] - r1[3] * r2[1];
        Lr[5] = r1[2] * r2[3] - r1[3] * r2[2];
        float n2 = 0.f;
#pragma unroll
        for (int j = 0; j < 6; ++j) n2 += Lr[j] * Lr[j];
        float inv = 1.f / fmaxf(sqrtf(n2), 1e-12f);
#pragma unroll
        for (int j = 0; j < 6; ++j) Lr[j] *= inv;
    }
    float decay = 1.f / (1.f + __expf(-decay_logits[h]));
    float l2d = log2f(decay);
    float bs = bias_scale[h] * exp2f(-(float)t * l2d);
    size_t base = (((size_t)(b * H_DIM + h)) * T_DIM + t) * 8;
    read8[base + 0] = __float2bfloat16(Lr[0]);
    read8[base + 1] = __float2bfloat16(Lr[1]);
    read8[base + 2] = __float2bfloat16(Lr[2]);
    read8[base + 3] = __float2bfloat16(Lr[3]);
    read8[base + 4] = __float2bfloat16(Lr[4]);
    read8[base + 5] = __float2bfloat16(Lr[5]);
    read8[base + 6] = __float2bfloat16(0.f);
    read8[base + 7] = __float2bfloat16(0.f);
    jw8[base + 0] = __float2bfloat16(Lw[5] * bs);
    jw8[base + 1] = __float2bfloat16(-Lw[4] * bs);
    jw8[base + 2] = __float2bfloat16(Lw[3] * bs);
    jw8[base + 3] = __float2bfloat16(Lw[2] * bs);
    jw8[base + 4] = __float2bfloat16(-Lw[1] * bs);
    jw8[base + 5] = __float2bfloat16(Lw[0] * bs);
    jw8[base + 6] = __float2bfloat16(0.f);
    jw8[base + 7] = __float2bfloat16(0.f);
}

// Swapped-QK softmax step (R9): S computed as mfma(K,Q) so each lane holds
// the full P sub-row for q = rq+ln at k = kb+8*lg+{0..7} (evens in ze, odds
// in zo). In-lane exp2 + pack -> the PV A-fragment DIRECTLY. No LDS bounce.
template<bool DIAG>
__device__ __forceinline__ bf16x8 tile_step_sw(
    const f32x4& ze, const f32x4& zo, const f32x4& ie, const f32x4& io,
    int qrow, int kb, int lg, float aq, float& lp)
{
    bf16x8 pf;
    float s = lp;
#pragma unroll
    for (int r = 0; r < 4; ++r) {
        float pe, po;
        if (DIAG) {
            int de = qrow - (kb + 8 * lg + 2 * r);
            float se = ze[r] + ((de > 0) ? ie[r] * aq : 0.f);
            pe = (de < 0) ? 0.f : __builtin_amdgcn_exp2f(se);
            int dd = de - 1;
            float so = zo[r] + ((dd > 0) ? io[r] * aq : 0.f);
            po = (dd < 0) ? 0.f : __builtin_amdgcn_exp2f(so);
        } else {
            pe = __builtin_amdgcn_exp2f(fmaf(ie[r], aq, ze[r]));
            po = __builtin_amdgcn_exp2f(fmaf(io[r], aq, zo[r]));
        }
        pf[2 * r]     = (__bf16)pe;
        pf[2 * r + 1] = (__bf16)po;
        s += pe + po;
    }
    lp = s;
    return pf;
}

// Attention: 4 Q-tiles/block (R7) + 64-wide k (R8) + swapped-QK in-register
// P (R9). Best-known config: 81.4us, VGPR 172, no spill. Frozen this round.
#define MFMA_BF16 __builtin_amdgcn_mfma_f32_16x16x32_bf16

#define QKSM64(T) { \
    const bool last##T = (c == nc##T - 1); \
    { f32x4 ze = {}, zo = {}, ie = {}, io = {}; \
      ze = MFMA_BF16(k00, q##T##0, ze, 0, 0, 0); \
      ze = MFMA_BF16(k01, q##T##1, ze, 0, 0, 0); \
      zo = MFMA_BF16(k10, q##T##0, zo, 0, 0, 0); \
      zo = MFMA_BF16(k11, q##T##1, zo, 0, 0, 0); \
      ie = MFMA_BF16(j0, rf##T, ie, 0, 0, 0); \
      io = MFMA_BF16(j1, rf##T, io, 0, 0, 0); \
      if (last##T && (t##T & 3) < 2) \
          pfa##T = tile_step_sw<true >(ze, zo, ie, io, qr##T, kb, lg, aq##T, lp##T); \
      else \
          pfa##T = tile_step_sw<false>(ze, zo, ie, io, qr##T, kb, lg, aq##T, lp##T); \
    } \
    { f32x4 ze = {}, zo = {}, ie = {}, io = {}; \
      ze = MFMA_BF16(k00b, q##T##0, ze, 0, 0, 0); \
      ze = MFMA_BF16(k01b, q##T##1, ze, 0, 0, 0); \
      zo = MFMA_BF16(k10b, q##T##0, zo, 0, 0, 0); \
      zo = MFMA_BF16(k11b, q##T##1, zo, 0, 0, 0); \
      ie = MFMA_BF16(j0b, rf##T, ie, 0, 0, 0); \
      io = MFMA_BF16(j1b, rf##T, io, 0, 0, 0); \
      if (last##T) \
          pfb##T = tile_step_sw<true >(ze, zo, ie, io, qr##T, kb + 32, lg, aq##T, lp##T); \
      else \
          pfb##T = tile_step_sw<false>(ze, zo, ie, io, qr##T, kb + 32, lg, aq##T, lp##T); \
    } }

#define PVSTEP64(T) { \
    o##T[0] = MFMA_BF16(pfa##T, vf0, o##T[0], 0, 0, 0); \
    o##T[1] = MFMA_BF16(pfa##T, vf1, o##T[1], 0, 0, 0); \
    o##T[2] = MFMA_BF16(pfa##T, vf2, o##T[2], 0, 0, 0); \
    o##T[3] = MFMA_BF16(pfa##T, vf3, o##T[3], 0, 0, 0); \
    o##T[0] = MFMA_BF16(pfb##T, vf4, o##T[0], 0, 0, 0); \
    o##T[1] = MFMA_BF16(pfb##T, vf5, o##T[1], 0, 0, 0); \
    o##T[2] = MFMA_BF16(pfb##T, vf6, o##T[2], 0, 0, 0); \
    o##T[3] = MFMA_BF16(pfb##T, vf7, o##T[3], 0, 0, 0); }

#define WRITE_OUT(T) { \
    __syncthreads(); \
    if (lg == 0) sm[wave * 1088 + ln * 68 + 64] = lp##T; \
    _Pragma("unroll") \
    for (int r = 0; r < 4; ++r) { \
        _Pragma("unroll") \
        for (int nt = 0; nt < 4; ++nt) \
            sm[wave * 1088 + (lg * 4 + r) * 68 + nt * 16 + ln] = o##T[nt][r]; \
    } \
    __syncthreads(); \
    { \
        float l = 0.f; \
        _Pragma("unroll") \
        for (int w = 0; w < 4; ++w) l += sm[w * 1088 + row * 68 + 64]; \
        float4 acc = {0.f, 0.f, 0.f, 0.f}; \
        _Pragma("unroll") \
        for (int w = 0; w < 4; ++w) { \
            float4 t = *(const float4*)&sm[w * 1088 + row * 68 + c4]; \
            acc.x += t.x; acc.y += t.y; acc.z += t.z; acc.w += t.w; \
        } \
        float invl = 1.f / l; \
        bh4 pk; \
        pk.v[0] = __float2bfloat16(acc.x * invl); \
        pk.v[1] = __float2bfloat16(acc.y * invl); \
        pk.v[2] = __float2bfloat16(acc.z * invl); \
        pk.v[3] = __float2bfloat16(acc.w * invl); \
        size_t tok = (size_t)b * T_DIM + rq##T + row; \
        *(uint2*)&attn_out[tok * D_DIM + h * DH + c4] = __builtin_bit_cast(uint2, pk); \
    } }

__global__ __launch_bounds__(256) void attn_kernel(
    const bhalf* __restrict__ q, const bhalf* __restrict__ k, const bhalf* __restrict__ vt,
    const bhalf* __restrict__ read8, const bhalf* __restrict__ jw8,
    const float* __restrict__ decay_logits, bhalf* __restrict__ attn_out)
{
    __shared__ float sm[4352];   // 17408 B: epilogue only
    const int wave = threadIdx.x >> 6, lane = threadIdx.x & 63;
    const int ln = lane & 15, lg = lane >> 4;
    const int bx = blockIdx.x;               // 0..1023
    const int xcd = bx & 7;
    const int slot = bx >> 3;                // 0..127
    const int hbid = xcd * 4 + (slot >> 5);  // 0..31
    const int h = hbid & 15, b = hbid >> 4;
    const int j = slot & 31;
    const int tA = j, tB = 63 - j, tC = 64 + j, tD = 127 - j;
    const int rqA = tA * 16, rqB = tB * 16, rqC = tC * 16, rqD = tD * 16;
    const int ncA = (tA >> 2) + 1, ncB = (tB >> 2) + 1;
    const int ncC = (tC >> 2) + 1, ncD = (tD >> 2) + 1;
    const int qrA = rqA + ln, qrB = rqB + ln, qrC = rqC + ln, qrD = rqD + ln;
    const size_t hb = (size_t)(b * H_DIM + h);
    const bhalf* qh = q + hb * T_DIM * DH;
    const bhalf* kh = k + hb * T_DIM * DH;
    const bhalf* vh = vt + hb * DH * T_DIM;
    const bhalf* r8 = read8 + hb * T_DIM * 8;
    const bhalf* j8 = jw8 + hb * T_DIM * 8;

    bf16x8 zf = zero_bf16x8();
    bf16x8 qA0 = load_bf16x8(qh + (rqA + ln) * DH + lg * 8);
    bf16x8 qA1 = load_bf16x8(qh + (rqA + ln) * DH + 32 + lg * 8);
    bf16x8 qB0 = load_bf16x8(qh + (rqB + ln) * DH + lg * 8);
    bf16x8 qB1 = load_bf16x8(qh + (rqB + ln) * DH + 32 + lg * 8);
    bf16x8 qC0 = load_bf16x8(qh + (rqC + ln) * DH + lg * 8);
    bf16x8 qC1 = load_bf16x8(qh + (rqC + ln) * DH + 32 + lg * 8);
    bf16x8 qD0 = load_bf16x8(qh + (rqD + ln) * DH + lg * 8);
    bf16x8 qD1 = load_bf16x8(qh + (rqD + ln) * DH + 32 + lg * 8);
    bf16x8 rfA = (lane < 16) ? load_bf16x8(r8 + (size_t)(rqA + ln) * 8) : zf;
    bf16x8 rfB = (lane < 16) ? load_bf16x8(r8 + (size_t)(rqB + ln) * 8) : zf;
    bf16x8 rfC = (lane < 16) ? load_bf16x8(r8 + (size_t)(rqC + ln) * 8) : zf;
    bf16x8 rfD = (lane < 16) ? load_bf16x8(r8 + (size_t)(rqD + ln) * 8) : zf;

    float decay = 1.f / (1.f + __expf(-decay_logits[h]));
    float l2d = log2f(decay);
    const float LOG2E = 1.44269504f;
    float aqA = LOG2E * __builtin_amdgcn_exp2f((float)qrA * l2d);
    float aqB = LOG2E * __builtin_amdgcn_exp2f((float)qrB * l2d);
    float aqC = LOG2E * __builtin_amdgcn_exp2f((float)qrC * l2d);
    float aqD = LOG2E * __builtin_amdgcn_exp2f((float)qrD * l2d);

    f32x4 oA[4] = {}, oB[4] = {}, oC[4] = {}, oD[4] = {};
    float lpA = 0.f, lpB = 0.f, lpC = 0.f, lpD = 0.f;

    for (int c = wave; c < ncD; c += 4) {
        const int kb = c * 64;
        bf16x8 k00 = load_bf16x8(kh + (kb + 2 * ln) * DH + lg * 8);
        bf16x8 k01 = load_bf16x8(kh + (kb + 2 * ln) * DH + 32 + lg * 8);
        bf16x8 k10 = load_bf16x8(kh + (kb + 2 * ln + 1) * DH + lg * 8);
        bf16x8 k11 = load_bf16x8(kh + (kb + 2 * ln + 1) * DH + 32 + lg * 8);
        bf16x8 j0 = (lane < 16) ? load_bf16x8(j8 + (size_t)(kb + 2 * ln) * 8) : zf;
        bf16x8 j1 = (lane < 16) ? load_bf16x8(j8 + (size_t)(kb + 2 * ln + 1) * 8) : zf;
        bf16x8 k00b = load_bf16x8(kh + (kb + 32 + 2 * ln) * DH + lg * 8);
        bf16x8 k01b = load_bf16x8(kh + (kb + 32 + 2 * ln) * DH + 32 + lg * 8);
        bf16x8 k10b = load_bf16x8(kh + (kb + 32 + 2 * ln + 1) * DH + lg * 8);
        bf16x8 k11b = load_bf16x8(kh + (kb + 32 + 2 * ln + 1) * DH + 32 + lg * 8);
        bf16x8 j0b = (lane < 16) ? load_bf16x8(j8 + (size_t)(kb + 32 + 2 * ln) * 8) : zf;
        bf16x8 j1b = (lane < 16) ? load_bf16x8(j8 + (size_t)(kb + 32 + 2 * ln + 1) * 8) : zf;
        bf16x8 vf0 = load_bf16x8(vh + (size_t)(ln) * T_DIM + kb + lg * 8);
        bf16x8 vf1 = load_bf16x8(vh + (size_t)(16 + ln) * T_DIM + kb + lg * 8);
        bf16x8 vf2 = load_bf16x8(vh + (size_t)(32 + ln) * T_DIM + kb + lg * 8);
        bf16x8 vf3 = load_bf16x8(vh + (size_t)(48 + ln) * T_DIM + kb + lg * 8);
        bf16x8 vf4 = load_bf16x8(vh + (size_t)(ln) * T_DIM + kb + 32 + lg * 8);
        bf16x8 vf5 = load_bf16x8(vh + (size_t)(16 + ln) * T_DIM + kb + 32 + lg * 8);
        bf16x8 vf6 = load_bf16x8(vh + (size_t)(32 + ln) * T_DIM + kb + 32 + lg * 8);
        bf16x8 vf7 = load_bf16x8(vh + (size_t)(48 + ln) * T_DIM + kb + 32 + lg * 8);
        const bool doC = (c < ncC), doB = (c < ncB), doA = (c < ncA);

        bf16x8 pfaD, pfbD, pfaC, pfbC, pfaB, pfbB, pfaA, pfbA;
        QKSM64(D);
        if (doC) QKSM64(C);
        if (doB) QKSM64(B);
        if (doA) QKSM64(A);

        PVSTEP64(D);
        if (doC) PVSTEP64(C);
        if (doB) PVSTEP64(B);
        if (doA) PVSTEP64(A);
    }

    lpA += __shfl_xor(lpA, 16); lpA += __shfl_xor(lpA, 32);
    lpB += __shfl_xor(lpB, 16); lpB += __shfl_xor(lpB, 32);
    lpC += __shfl_xor(lpC, 16); lpC += __shfl_xor(lpC, 32);
    lpD += __shfl_xor(lpD, 16); lpD += __shfl_xor(lpD, 32);

    const int row = threadIdx.x >> 4;
    const int c4 = (threadIdx.x & 15) * 4;

    WRITE_OUT(A);
    WRITE_OUT(B);
    WRITE_OUT(C);
    WRITE_OUT(D);
}

extern "C" void kernel_launch(void* const* d_in, const int* in_sizes, int n_in,
                              void* d_out, int out_size, void* d_ws, size_t ws_size,
                              hipStream_t stream)
{
    const float* x    = (const float*)d_in[0];
    const float* wqkv = (const float*)d_in[1];
    const float* bqkv = (const float*)d_in[2];
    const float* w1w  = (const float*)d_in[3];
    const float* w2w  = (const float*)d_in[4];
    const float* w1r  = (const float*)d_in[5];
    const float* w2r  = (const float*)d_in[6];
    const float* wout = (const float*)d_in[7];
    const float* bout = (const float*)d_in[8];
    const float* dlog = (const float*)d_in[9];
    const float* bsc  = (const float*)d_in[10];
    float* out = (float*)d_out;

    char* ws = (char*)d_ws;
    bhalf* qb    = (bhalf*)(ws);                 // [B,H,T,64] bf16   8388608 B
    bhalf* kbuf  = (bhalf*)(ws + 8388608);       // [B,H,T,64] bf16   8388608 B
    bhalf* vtb   = (bhalf*)(ws + 16777216);      // [B,H,64,T] bf16   8388608 B
    bhalf* r8    = (bhalf*)(ws + 25165824);      // [B,H,T,8]  bf16   1048576 B
    bhalf* j8    = (bhalf*)(ws + 26214400);      // [B,H,T,8]  bf16   1048576 B
    float* proj  = (float*)(ws + 27262976);      // [B*T,256]  f32    4194304 B
    bhalf* ao    = (bhalf*)(ws + 31457280);      // [B*T,1024] bf16   8388608 B
    bhalf* woutbf = (bhalf*)(ws + 39845888);     // [1024,1024] bf16  2097152 B

    bhalf* xbf  = (bhalf*)d_out;                      //  8388608 B
    bhalf* wcat = (bhalf*)((char*)d_out + 8388608);   //  6815744 B (3328x1024)

    cvt_all<<<4224, 256, 0, stream>>>(x, wqkv, w1w, w2w, w1r, w2r, wout, xbf, wcat, woutbf);
    qkv_lines_gemm128<<<dim3(32, 26), 256, 0, stream>>>(xbf, wcat, bqkv, qb, kbuf, vtb, proj);
    build_lines<<<256, 256, 0, stream>>>(proj, bsc, dlog, r8, j8);
    attn_kernel<<<1024, 256, 0, stream>>>(qb, kbuf, vtb, r8, j8, dlog, ao);
    out_gemm64<<<dim3(64, 16), 256, 0, stream>>>(ao, woutbf, bout, out);
}

// Round 11
// 249.154 us; speedup vs baseline: 1.1575x; 1.0124x over previous
//
#include <hip/hip_runtime.h>
#include <hip/hip_bf16.h>

using bhalf = __hip_bfloat16;
typedef __bf16 bf16x8 __attribute__((ext_vector_type(8)));
typedef __bf16 bf16x2 __attribute__((ext_vector_type(2)));
typedef float f32x4 __attribute__((ext_vector_type(4)));

#define B_DIM 2
#define T_DIM 2048
#define D_DIM 1024
#define H_DIM 16
#define DH 64

struct bh8 { bhalf v[8]; };
struct bh4 { bhalf v[4]; };

__device__ __forceinline__ bf16x8 load_bf16x8(const bhalf* p) {
    return __builtin_bit_cast(bf16x8, *(const uint4*)p);
}
__device__ __forceinline__ bf16x8 zero_bf16x8() {
    uint4 z; z.x = 0; z.y = 0; z.z = 0; z.w = 0;
    return __builtin_bit_cast(bf16x8, z);
}
__device__ __forceinline__ void stage8_cvt(bhalf* dst, const float* src) {
    float4 a = *(const float4*)src;
    float4 b = *(const float4*)(src + 4);
    bh8 t;
    t.v[0] = __float2bfloat16(a.x); t.v[1] = __float2bfloat16(a.y);
    t.v[2] = __float2bfloat16(a.z); t.v[3] = __float2bfloat16(a.w);
    t.v[4] = __float2bfloat16(b.x); t.v[5] = __float2bfloat16(b.y);
    t.v[6] = __float2bfloat16(b.z); t.v[7] = __float2bfloat16(b.w);
    *(uint4*)dst = __builtin_bit_cast(uint4, t);
}

// async 16B global -> LDS (wave-uniform LDS base + lane*16)
#define GLD16(gp, lp) __builtin_amdgcn_global_load_lds( \
    (const __attribute__((address_space(1))) void*)(gp), \
    (__attribute__((address_space(3))) void*)(lp), 16, 0, 0)

// Segment sizes (elements)
#define SX  4194304
#define SW  3145728
#define SL  65536
#define SO  1048576
__global__ __launch_bounds__(256) void cvt_all(
    const float* __restrict__ x, const float* __restrict__ wqkv,
    const float* __restrict__ w1w, const float* __restrict__ w2w,
    const float* __restrict__ w1r, const float* __restrict__ w2r,
    const float* __restrict__ wout,
    bhalf* __restrict__ xbf, bhalf* __restrict__ wcat, bhalf* __restrict__ woutbf)
{
    int i = (blockIdx.x * 256 + threadIdx.x) * 8;
    if (i < SX) { stage8_cvt(xbf + i, x + i); return; }
    i -= SX;
    if (i < SW) { stage8_cvt(wcat + i, wqkv + i); return; }
    i -= SW;
    if (i < SL) { stage8_cvt(wcat + SW + i, w1w + i); return; }
    i -= SL;
    if (i < SL) { stage8_cvt(wcat + SW + SL + i, w2w + i); return; }
    i -= SL;
    if (i < SL) { stage8_cvt(wcat + SW + 2 * SL + i, w1r + i); return; }
    i -= SL;
    if (i < SL) { stage8_cvt(wcat + SW + 3 * SL + i, w2r + i); return; }
    i -= SL;
    if (i < SO) { stage8_cvt(woutbf + i, wout + i); }
}

// ---------------- 128x128 tile GEMM: C = A(128xK) * B(128xK)^T ----------------
// C rows = A-tile rows (wr/mt/lg*4+r), C cols = B-tile rows (wc/nt/ln).
__device__ __forceinline__ void gemm128_mainloop(
    const bhalf* __restrict__ A, const bhalf* __restrict__ B, int K,
    bhalf* As, bhalf* Bs, f32x4 acc[4][4])
{
    const int tid = threadIdx.x;
    const int wave = tid >> 6, lane = tid & 63;
    const int ln = lane & 15, lg = lane >> 4;
    const int wr = (wave >> 1) * 64, wc = (wave & 1) * 64;
    const int lrow = lane >> 3;
    const int lcol = (lane & 7) * 8;

    for (int kt = 0; kt < K; kt += 64) {
        __syncthreads();
#pragma unroll
        for (int i = 0; i < 4; ++i) {
            int idx = __builtin_amdgcn_readfirstlane(wave * 4 + i);
            GLD16(A + (size_t)(idx * 8 + lrow) * K + kt + lcol, As + idx * 512);
            GLD16(B + (size_t)(idx * 8 + lrow) * K + kt + lcol, Bs + idx * 512);
        }
        __syncthreads();
#pragma unroll
        for (int ks = 0; ks < 2; ++ks) {
            bf16x8 af[4], bfr[4];
#pragma unroll
            for (int mt = 0; mt < 4; ++mt)
                af[mt] = load_bf16x8(As + (wr + mt * 16 + ln) * 64 + ks * 32 + lg * 8);
#pragma unroll
            for (int nt = 0; nt < 4; ++nt)
                bfr[nt] = load_bf16x8(Bs + (wc + nt * 16 + ln) * 64 + ks * 32 + lg * 8);
#pragma unroll
            for (int mt = 0; mt < 4; ++mt)
#pragma unroll
                for (int nt = 0; nt < 4; ++nt)
                    acc[mt][nt] = __builtin_amdgcn_mfma_f32_16x16x32_bf16(af[mt], bfr[nt], acc[mt][nt], 0, 0, 0);
        }
    }
}

// fused qkv + lines projection. Trips 0/1/3 run the mainloop with SWAPPED
// operands (A=weights, B=x) so C rows = features -> vectorized 8B/16B stores.
// trip 2 (v^T) keeps the original order (already packed over tokens).
// Q pre-scaled by 0.125*log2(e) (exp2-domain softmax).
__global__ __launch_bounds__(256) void qkv_lines_gemm128(
    const bhalf* __restrict__ x, const bhalf* __restrict__ wcat, const float* __restrict__ bqkv,
    bhalf* __restrict__ qo, bhalf* __restrict__ ko, bhalf* __restrict__ vt,
    float* __restrict__ proj)
{
    __shared__ bhalf As[128 * 64];
    __shared__ bhalf Bs[128 * 64];
    f32x4 acc[4][4] = {};
    const int wave = threadIdx.x >> 6, lane = threadIdx.x & 63;
    const int ln = lane & 15, lg = lane >> 4;
    const int wr = (wave >> 1) * 64, wc = (wave & 1) * 64;
    const int trip = (blockIdx.y * 128) >> 10;   // uniform per block

    if (trip == 2) {
        gemm128_mainloop(x + (size_t)blockIdx.x * 128 * D_DIM,
                         wcat + (size_t)blockIdx.y * 128 * D_DIM, D_DIM, As, Bs, acc);
        // v^T: pack 4 consecutive-t values -> one 8B store per (mt,nt)
#pragma unroll
        for (int nt = 0; nt < 4; ++nt) {
            int n = blockIdx.y * 128 + wc + nt * 16 + ln;
            float bias = bqkv[n];
            int h = (n >> 6) & 15, d = n & 63;
#pragma unroll
            for (int mt = 0; mt < 4; ++mt) {
                int tok0 = blockIdx.x * 128 + wr + mt * 16 + lg * 4;
                int b = tok0 >> 11, t0 = tok0 & (T_DIM - 1);
                bh4 pk;
#pragma unroll
                for (int r = 0; r < 4; ++r)
                    pk.v[r] = __float2bfloat16(acc[mt][nt][r] + bias);
                *(uint2*)&vt[(((size_t)(b * H_DIM + h)) * DH + d) * T_DIM + t0] =
                    __builtin_bit_cast(uint2, pk);
            }
        }
    } else {
        // swapped: C rows = weight features, C cols = tokens
        gemm128_mainloop(wcat + (size_t)blockIdx.y * 128 * D_DIM,
                         x + (size_t)blockIdx.x * 128 * D_DIM, D_DIM, As, Bs, acc);
#pragma unroll
        for (int mt = 0; mt < 4; ++mt) {
            int n0 = blockIdx.y * 128 + wr + mt * 16 + lg * 4;  // 4-aligned feature base
            int h = (n0 >> 6) & 15, d0 = n0 & 63;
            float4 b4 = {0.f, 0.f, 0.f, 0.f};
            if (trip < 3) b4 = *(const float4*)&bqkv[n0];
#pragma unroll
            for (int nt = 0; nt < 4; ++nt) {
                int tok = blockIdx.x * 128 + wc + nt * 16 + ln;
                int b = tok >> 11, t = tok & (T_DIM - 1);
                if (trip == 0) {
                    bh4 pk;   // 0.125 * log2(e) scale folded into Q
                    pk.v[0] = __float2bfloat16((acc[mt][nt][0] + b4.x) * 0.18033688f);
                    pk.v[1] = __float2bfloat16((acc[mt][nt][1] + b4.y) * 0.18033688f);
                    pk.v[2] = __float2bfloat16((acc[mt][nt][2] + b4.z) * 0.18033688f);
                    pk.v[3] = __float2bfloat16((acc[mt][nt][3] + b4.w) * 0.18033688f);
                    *(uint2*)&qo[(((size_t)(b * H_DIM + h)) * T_DIM + t) * DH + d0] =
                        __builtin_bit_cast(uint2, pk);
                } else if (trip == 1) {
                    bh4 pk;
                    pk.v[0] = __float2bfloat16(acc[mt][nt][0] + b4.x);
                    pk.v[1] = __float2bfloat16(acc[mt][nt][1] + b4.y);
                    pk.v[2] = __float2bfloat16(acc[mt][nt][2] + b4.z);
                    pk.v[3] = __float2bfloat16(acc[mt][nt][3] + b4.w);
                    *(uint2*)&ko[(((size_t)(b * H_DIM + h)) * T_DIM + t) * DH + d0] =
                        __builtin_bit_cast(uint2, pk);
                } else {  // trip == 3: proj, contiguous features -> float4
                    float4 v;
                    v.x = acc[mt][nt][0]; v.y = acc[mt][nt][1];
                    v.z = acc[mt][nt][2]; v.w = acc[mt][nt][3];
                    *(float4*)&proj[(size_t)tok * 256 + (n0 - 3072)] = v;
                }
            }
        }
    }
}

// R11: out projection 64x128 tile (64 features x 128 tokens), swapped
// orientation (A=w features, B=ao tokens). Per wave: 32x64 output (acc[2][4]),
// per K-step 16 MFMA : 12 ds_reads (vs 64^2's 16:20) and 6 GLD16 for 2x the
// FLOPs -- doubles MFMA amortization per staging/barrier round. Grid (32,16)
// = 512 blocks = 2/CU (keeps inter-block overlap; 1/CU 128^2 was slower).
// LDS 24KB. float4 stores (4 consecutive features per lane).
__global__ __launch_bounds__(256) void out_gemm64x128(
    const bhalf* __restrict__ a, const bhalf* __restrict__ w, const float* __restrict__ bo,
    float* __restrict__ out)
{
    __shared__ bhalf As[64 * 64];    //  8KB: 64 feature rows
    __shared__ bhalf Bs[128 * 64];   // 16KB: 128 token rows
    const int tid = threadIdx.x;
    const int wave = tid >> 6, lane = tid & 63;
    const int ln = lane & 15, lg = lane >> 4;
    const int lrow = lane >> 3;
    const int lcol = (lane & 7) * 8;
    const int fr = (wave >> 1) * 32;   // wave's feature-row base (0|32)
    const int tc = (wave & 1) * 64;    // wave's token-col base (0|64)
    const bhalf* A = w + (size_t)blockIdx.y * 64 * D_DIM;    // features
    const bhalf* B = a + (size_t)blockIdx.x * 128 * D_DIM;   // tokens
    f32x4 acc[2][4] = {};

    for (int kt = 0; kt < D_DIM; kt += 64) {
        __syncthreads();
#pragma unroll
        for (int i = 0; i < 2; ++i) {
            int idx = __builtin_amdgcn_readfirstlane(wave * 2 + i);
            GLD16(A + (size_t)(idx * 8 + lrow) * D_DIM + kt + lcol, As + idx * 512);
        }
#pragma unroll
        for (int i = 0; i < 4; ++i) {
            int idx = __builtin_amdgcn_readfirstlane(wave * 4 + i);
            GLD16(B + (size_t)(idx * 8 + lrow) * D_DIM + kt + lcol, Bs + idx * 512);
        }
        __syncthreads();
#pragma unroll
        for (int ks = 0; ks < 2; ++ks) {
            bf16x8 af[2], bfr[4];
#pragma unroll
            for (int i2 = 0; i2 < 2; ++i2)
                af[i2] = load_bf16x8(As + (fr + i2 * 16 + ln) * 64 + ks * 32 + lg * 8);
#pragma unroll
            for (int j = 0; j < 4; ++j)
                bfr[j] = load_bf16x8(Bs + (tc + j * 16 + ln) * 64 + ks * 32 + lg * 8);
#pragma unroll
            for (int i2 = 0; i2 < 2; ++i2)
#pragma unroll
                for (int j = 0; j < 4; ++j)
                    acc[i2][j] = __builtin_amdgcn_mfma_f32_16x16x32_bf16(af[i2], bfr[j], acc[i2][j], 0, 0, 0);
        }
    }
#pragma unroll
    for (int i2 = 0; i2 < 2; ++i2) {
        int n0 = blockIdx.y * 64 + fr + i2 * 16 + lg * 4;   // 4-aligned feature base
        float4 b4 = *(const float4*)&bo[n0];
#pragma unroll
        for (int j = 0; j < 4; ++j) {
            int tok = blockIdx.x * 128 + tc + j * 16 + ln;
            float4 v;
            v.x = acc[i2][j][0] + b4.x; v.y = acc[i2][j][1] + b4.y;
            v.z = acc[i2][j][2] + b4.z; v.w = acc[i2][j][3] + b4.w;
            *(float4*)&out[(size_t)tok * D_DIM + n0] = v;
        }
    }
}

__global__ __launch_bounds__(256) void build_lines(
    const float* __restrict__ proj, const float* __restrict__ bias_scale,
    const float* __restrict__ decay_logits,
    bhalf* __restrict__ read8, bhalf* __restrict__ jw8)
{
    int id = blockIdx.x * 256 + threadIdx.x;
    int tok = id >> 4, h = id & 15;
    int b = tok >> 11, t = tok & (T_DIM - 1);
    const float* pr = proj + (size_t)tok * 256;

    float p1[4], p2[4], r1[4], r2[4];
#pragma unroll
    for (int i = 0; i < 4; ++i) {
        p1[i] = (t > 0) ? pr[-256 + h * 4 + i] : 0.f;
        p2[i] = pr[64 + h * 4 + i];
        r1[i] = pr[128 + h * 4 + i];
        r2[i] = pr[192 + h * 4 + i];
    }
    float Lw[6], Lr[6];
    {
        Lw[0] = p1[0] * p2[1] - p1[1] * p2[0];
        Lw[1] = p1[0] * p2[2] - p1[2] * p2[0];
        Lw[2] = p1[0] * p2[3] - p1[3] * p2[0];
        Lw[3] = p1[1] * p2[2] - p1[2] * p2[1];
        Lw[4] = p1[1] * p2[3] - p1[3] * p2[1];
        Lw[5] = p1[2] * p2[3] - p1[3] * p2[2];
        float n2 = 0.f;
#pragma unroll
        for (int j = 0; j < 6; ++j) n2 += Lw[j] * Lw[j];
        float inv = 1.f / fmaxf(sqrtf(n2), 1e-12f);
#pragma unroll
        for (int j = 0; j < 6; ++j) Lw[j] *= inv;
    }
    {
        Lr[0] = r1[0] * r2[1] - r1[1] * r2[0];
        Lr[1] = r1[0] * r2[2] - r1[2] * r2[0];
        Lr[2] = r1[0] * r2[3] - r1[3] * r2[0];
        Lr[3] = r1[1] * r2[2] - r1[2] * r2[1];
        Lr[4] = r1[1] * r2[3] - r1[3] * r2[1];
        Lr[5] = r1[2] * r2[3] - r1[3] * r2[2];
        float n2 = 0.f;
#pragma unroll
        for (int j = 0; j < 6; ++j) n2 += Lr[j] * Lr[j];
        float inv = 1.f / fmaxf(sqrtf(n2), 1e-12f);
#pragma unroll
        for (int j = 0; j < 6; ++j) Lr[j] *= inv;
    }
    float decay = 1.f / (1.f + __expf(-decay_logits[h]));
    float l2d = log2f(decay);
    float bs = bias_scale[h] * exp2f(-(float)t * l2d);
    size_t base = (((size_t)(b * H_DIM + h)) * T_DIM + t) * 8;
    read8[base + 0] = __float2bfloat16(Lr[0]);
    read8[base + 1] = __float2bfloat16(Lr[1]);
    read8[base + 2] = __float2bfloat16(Lr[2]);
    read8[base + 3] = __float2bfloat16(Lr[3]);
    read8[base + 4] = __float2bfloat16(Lr[4]);
    read8[base + 5] = __float2bfloat16(Lr[5]);
    read8[base + 6] = __float2bfloat16(0.f);
    read8[base + 7] = __float2bfloat16(0.f);
    jw8[base + 0] = __float2bfloat16(Lw[5] * bs);
    jw8[base + 1] = __float2bfloat16(-Lw[4] * bs);
    jw8[base + 2] = __float2bfloat16(Lw[3] * bs);
    jw8[base + 3] = __float2bfloat16(Lw[2] * bs);
    jw8[base + 4] = __float2bfloat16(-Lw[1] * bs);
    jw8[base + 5] = __float2bfloat16(Lw[0] * bs);
    jw8[base + 6] = __float2bfloat16(0.f);
    jw8[base + 7] = __float2bfloat16(0.f);
}

// Swapped-QK softmax step (R9): S computed as mfma(K,Q) so each lane holds
// the full P sub-row for q = rq+ln at k = kb+8*lg+{0..7} (evens in ze, odds
// in zo). In-lane exp2 + pack -> the PV A-fragment DIRECTLY. No LDS bounce.
template<bool DIAG>
__device__ __forceinline__ bf16x8 tile_step_sw(
    const f32x4& ze, const f32x4& zo, const f32x4& ie, const f32x4& io,
    int qrow, int kb, int lg, float aq, float& lp)
{
    bf16x8 pf;
    float s = lp;
#pragma unroll
    for (int r = 0; r < 4; ++r) {
        float pe, po;
        if (DIAG) {
            int de = qrow - (kb + 8 * lg + 2 * r);
            float se = ze[r] + ((de > 0) ? ie[r] * aq : 0.f);
            pe = (de < 0) ? 0.f : __builtin_amdgcn_exp2f(se);
            int dd = de - 1;
            float so = zo[r] + ((dd > 0) ? io[r] * aq : 0.f);
            po = (dd < 0) ? 0.f : __builtin_amdgcn_exp2f(so);
        } else {
            pe = __builtin_amdgcn_exp2f(fmaf(ie[r], aq, ze[r]));
            po = __builtin_amdgcn_exp2f(fmaf(io[r], aq, zo[r]));
        }
        pf[2 * r]     = (__bf16)pe;
        pf[2 * r + 1] = (__bf16)po;
        s += pe + po;
    }
    lp = s;
    return pf;
}

// Attention: 4 Q-tiles/block (R7) + 64-wide k (R8) + swapped-QK in-register
// P (R9). Best-known config: 81.4us, VGPR 172, no spill. Frozen.
#define MFMA_BF16 __builtin_amdgcn_mfma_f32_16x16x32_bf16

#define QKSM64(T) { \
    const bool last##T = (c == nc##T - 1); \
    { f32x4 ze = {}, zo = {}, ie = {}, io = {}; \
      ze = MFMA_BF16(k00, q##T##0, ze, 0, 0, 0); \
      ze = MFMA_BF16(k01, q##T##1, ze, 0, 0, 0); \
      zo = MFMA_BF16(k10, q##T##0, zo, 0, 0, 0); \
      zo = MFMA_BF16(k11, q##T##1, zo, 0, 0, 0); \
      ie = MFMA_BF16(j0, rf##T, ie, 0, 0, 0); \
      io = MFMA_BF16(j1, rf##T, io, 0, 0, 0); \
      if (last##T && (t##T & 3) < 2) \
          pfa##T = tile_step_sw<true >(ze, zo, ie, io, qr##T, kb, lg, aq##T, lp##T); \
      else \
          pfa##T = tile_step_sw<false>(ze, zo, ie, io, qr##T, kb, lg, aq##T, lp##T); \
    } \
    { f32x4 ze = {}, zo = {}, ie = {}, io = {}; \
      ze = MFMA_BF16(k00b, q##T##0, ze, 0, 0, 0); \
      ze = MFMA_BF16(k01b, q##T##1, ze, 0, 0, 0); \
      zo = MFMA_BF16(k10b, q##T##0, zo, 0, 0, 0); \
      zo = MFMA_BF16(k11b, q##T##1, zo, 0, 0, 0); \
      ie = MFMA_BF16(j0b, rf##T, ie, 0, 0, 0); \
      io = MFMA_BF16(j1b, rf##T, io, 0, 0, 0); \
      if (last##T) \
          pfb##T = tile_step_sw<true >(ze, zo, ie, io, qr##T, kb + 32, lg, aq##T, lp##T); \
      else \
          pfb##T = tile_step_sw<false>(ze, zo, ie, io, qr##T, kb + 32, lg, aq##T, lp##T); \
    } }

#define PVSTEP64(T) { \
    o##T[0] = MFMA_BF16(pfa##T, vf0, o##T[0], 0, 0, 0); \
    o##T[1] = MFMA_BF16(pfa##T, vf1, o##T[1], 0, 0, 0); \
    o##T[2] = MFMA_BF16(pfa##T, vf2, o##T[2], 0, 0, 0); \
    o##T[3] = MFMA_BF16(pfa##T, vf3, o##T[3], 0, 0, 0); \
    o##T[0] = MFMA_BF16(pfb##T, vf4, o##T[0], 0, 0, 0); \
    o##T[1] = MFMA_BF16(pfb##T, vf5, o##T[1], 0, 0, 0); \
    o##T[2] = MFMA_BF16(pfb##T, vf6, o##T[2], 0, 0, 0); \
    o##T[3] = MFMA_BF16(pfb##T, vf7, o##T[3], 0, 0, 0); }

#define WRITE_OUT(T) { \
    __syncthreads(); \
    if (lg == 0) sm[wave * 1088 + ln * 68 + 64] = lp##T; \
    _Pragma("unroll") \
    for (int r = 0; r < 4; ++r) { \
        _Pragma("unroll") \
        for (int nt = 0; nt < 4; ++nt) \
            sm[wave * 1088 + (lg * 4 + r) * 68 + nt * 16 + ln] = o##T[nt][r]; \
    } \
    __syncthreads(); \
    { \
        float l = 0.f; \
        _Pragma("unroll") \
        for (int w = 0; w < 4; ++w) l += sm[w * 1088 + row * 68 + 64]; \
        float4 acc = {0.f, 0.f, 0.f, 0.f}; \
        _Pragma("unroll") \
        for (int w = 0; w < 4; ++w) { \
            float4 t = *(const float4*)&sm[w * 1088 + row * 68 + c4]; \
            acc.x += t.x; acc.y += t.y; acc.z += t.z; acc.w += t.w; \
        } \
        float invl = 1.f / l; \
        bh4 pk; \
        pk.v[0] = __float2bfloat16(acc.x * invl); \
        pk.v[1] = __float2bfloat16(acc.y * invl); \
        pk.v[2] = __float2bfloat16(acc.z * invl); \
        pk.v[3] = __float2bfloat16(acc.w * invl); \
        size_t tok = (size_t)b * T_DIM + rq##T + row; \
        *(uint2*)&attn_out[tok * D_DIM + h * DH + c4] = __builtin_bit_cast(uint2, pk); \
    } }

__global__ __launch_bounds__(256) void attn_kernel(
    const bhalf* __restrict__ q, const bhalf* __restrict__ k, const bhalf* __restrict__ vt,
    const bhalf* __restrict__ read8, const bhalf* __restrict__ jw8,
    const float* __restrict__ decay_logits, bhalf* __restrict__ attn_out)
{
    __shared__ float sm[4352];   // 17408 B: epilogue only
    const int wave = threadIdx.x >> 6, lane = threadIdx.x & 63;
    const int ln = lane & 15, lg = lane >> 4;
    const int bx = blockIdx.x;               // 0..1023
    const int xcd = bx & 7;
    const int slot = bx >> 3;                // 0..127
    const int hbid = xcd * 4 + (slot >> 5);  // 0..31
    const int h = hbid & 15, b = hbid >> 4;
    const int j = slot & 31;
    const int tA = j, tB = 63 - j, tC = 64 + j, tD = 127 - j;
    const int rqA = tA * 16, rqB = tB * 16, rqC = tC * 16, rqD = tD * 16;
    const int ncA = (tA >> 2) + 1, ncB = (tB >> 2) + 1;
    const int ncC = (tC >> 2) + 1, ncD = (tD >> 2) + 1;
    const int qrA = rqA + ln, qrB = rqB + ln, qrC = rqC + ln, qrD = rqD + ln;
    const size_t hb = (size_t)(b * H_DIM + h);
    const bhalf* qh = q + hb * T_DIM * DH;
    const bhalf* kh = k + hb * T_DIM * DH;
    const bhalf* vh = vt + hb * DH * T_DIM;
    const bhalf* r8 = read8 + hb * T_DIM * 8;
    const bhalf* j8 = jw8 + hb * T_DIM * 8;

    bf16x8 zf = zero_bf16x8();
    bf16x8 qA0 = load_bf16x8(qh + (rqA + ln) * DH + lg * 8);
    bf16x8 qA1 = load_bf16x8(qh + (rqA + ln) * DH + 32 + lg * 8);
    bf16x8 qB0 = load_bf16x8(qh + (rqB + ln) * DH + lg * 8);
    bf16x8 qB1 = load_bf16x8(qh + (rqB + ln) * DH + 32 + lg * 8);
    bf16x8 qC0 = load_bf16x8(qh + (rqC + ln) * DH + lg * 8);
    bf16x8 qC1 = load_bf16x8(qh + (rqC + ln) * DH + 32 + lg * 8);
    bf16x8 qD0 = load_bf16x8(qh + (rqD + ln) * DH + lg * 8);
    bf16x8 qD1 = load_bf16x8(qh + (rqD + ln) * DH + 32 + lg * 8);
    bf16x8 rfA = (lane < 16) ? load_bf16x8(r8 + (size_t)(rqA + ln) * 8) : zf;
    bf16x8 rfB = (lane < 16) ? load_bf16x8(r8 + (size_t)(rqB + ln) * 8) : zf;
    bf16x8 rfC = (lane < 16) ? load_bf16x8(r8 + (size_t)(rqC + ln) * 8) : zf;
    bf16x8 rfD = (lane < 16) ? load_bf16x8(r8 + (size_t)(rqD + ln) * 8) : zf;

    float decay = 1.f / (1.f + __expf(-decay_logits[h]));
    float l2d = log2f(decay);
    const float LOG2E = 1.44269504f;
    float aqA = LOG2E * __builtin_amdgcn_exp2f((float)qrA * l2d);
    float aqB = LOG2E * __builtin_amdgcn_exp2f((float)qrB * l2d);
    float aqC = LOG2E * __builtin_amdgcn_exp2f((float)qrC * l2d);
    float aqD = LOG2E * __builtin_amdgcn_exp2f((float)qrD * l2d);

    f32x4 oA[4] = {}, oB[4] = {}, oC[4] = {}, oD[4] = {};
    float lpA = 0.f, lpB = 0.f, lpC = 0.f, lpD = 0.f;

    for (int c = wave; c < ncD; c += 4) {
        const int kb = c * 64;
        bf16x8 k00 = load_bf16x8(kh + (kb + 2 * ln) * DH + lg * 8);
        bf16x8 k01 = load_bf16x8(kh + (kb + 2 * ln) * DH + 32 + lg * 8);
        bf16x8 k10 = load_bf16x8(kh + (kb + 2 * ln + 1) * DH + lg * 8);
        bf16x8 k11 = load_bf16x8(kh + (kb + 2 * ln + 1) * DH + 32 + lg * 8);
        bf16x8 j0 = (lane < 16) ? load_bf16x8(j8 + (size_t)(kb + 2 * ln) * 8) : zf;
        bf16x8 j1 = (lane < 16) ? load_bf16x8(j8 + (size_t)(kb + 2 * ln + 1) * 8) : zf;
        bf16x8 k00b = load_bf16x8(kh + (kb + 32 + 2 * ln) * DH + lg * 8);
        bf16x8 k01b = load_bf16x8(kh + (kb + 32 + 2 * ln) * DH + 32 + lg * 8);
        bf16x8 k10b = load_bf16x8(kh + (kb + 32 + 2 * ln + 1) * DH + lg * 8);
        bf16x8 k11b = load_bf16x8(kh + (kb + 32 + 2 * ln + 1) * DH + 32 + lg * 8);
        bf16x8 j0b = (lane < 16) ? load_bf16x8(j8 + (size_t)(kb + 32 + 2 * ln) * 8) : zf;
        bf16x8 j1b = (lane < 16) ? load_bf16x8(j8 + (size_t)(kb + 32 + 2 * ln + 1) * 8) : zf;
        bf16x8 vf0 = load_bf16x8(vh + (size_t)(ln) * T_DIM + kb + lg * 8);
        bf16x8 vf1 = load_bf16x8(vh + (size_t)(16 + ln) * T_DIM + kb + lg * 8);
        bf16x8 vf2 = load_bf16x8(vh + (size_t)(32 + ln) * T_DIM + kb + lg * 8);
        bf16x8 vf3 = load_bf16x8(vh + (size_t)(48 + ln) * T_DIM + kb + lg * 8);
        bf16x8 vf4 = load_bf16x8(vh + (size_t)(ln) * T_DIM + kb + 32 + lg * 8);
        bf16x8 vf5 = load_bf16x8(vh + (size_t)(16 + ln) * T_DIM + kb + 32 + lg * 8);
        bf16x8 vf6 = load_bf16x8(vh + (size_t)(32 + ln) * T_DIM + kb + 32 + lg * 8);
        bf16x8 vf7 = load_bf16x8(vh + (size_t)(48 + ln) * T_DIM + kb + 32 + lg * 8);
        const bool doC = (c < ncC), doB = (c < ncB), doA = (c < ncA);

        bf16x8 pfaD, pfbD, pfaC, pfbC, pfaB, pfbB, pfaA, pfbA;
        QKSM64(D);
        if (doC) QKSM64(C);
        if (doB) QKSM64(B);
        if (doA) QKSM64(A);

        PVSTEP64(D);
        if (doC) PVSTEP64(C);
        if (doB) PVSTEP64(B);
        if (doA) PVSTEP64(A);
    }

    lpA += __shfl_xor(lpA, 16); lpA += __shfl_xor(lpA, 32);
    lpB += __shfl_xor(lpB, 16); lpB += __shfl_xor(lpB, 32);
    lpC += __shfl_xor(lpC, 16); lpC += __shfl_xor(lpC, 32);
    lpD += __shfl_xor(lpD, 16); lpD += __shfl_xor(lpD, 32);

    const int row = threadIdx.x >> 4;
    const int c4 = (threadIdx.x & 15) * 4;

    WRITE_OUT(A);
    WRITE_OUT(B);
    WRITE_OUT(C);
    WRITE_OUT(D);
}

extern "C" void kernel_launch(void* const* d_in, const int* in_sizes, int n_in,
                              void* d_out, int out_size, void* d_ws, size_t ws_size,
                              hipStream_t stream)
{
    const float* x    = (const float*)d_in[0];
    const float* wqkv = (const float*)d_in[1];
    const float* bqkv = (const float*)d_in[2];
    const float* w1w  = (const float*)d_in[3];
    const float* w2w  = (const float*)d_in[4];
    const float* w1r  = (const float*)d_in[5];
    const float* w2r  = (const float*)d_in[6];
    const float* wout = (const float*)d_in[7];
    const float* bout = (const float*)d_in[8];
    const float* dlog = (const float*)d_in[9];
    const float* bsc  = (const float*)d_in[10];
    float* out = (float*)d_out;

    char* ws = (char*)d_ws;
    bhalf* qb    = (bhalf*)(ws);                 // [B,H,T,64] bf16   8388608 B
    bhalf* kbuf  = (bhalf*)(ws + 8388608);       // [B,H,T,64] bf16   8388608 B
    bhalf* vtb   = (bhalf*)(ws + 16777216);      // [B,H,64,T] bf16   8388608 B
    bhalf* r8    = (bhalf*)(ws + 25165824);      // [B,H,T,8]  bf16   1048576 B
    bhalf* j8    = (bhalf*)(ws + 26214400);      // [B,H,T,8]  bf16   1048576 B
    float* proj  = (float*)(ws + 27262976);      // [B*T,256]  f32    4194304 B
    bhalf* ao    = (bhalf*)(ws + 31457280);      // [B*T,1024] bf16   8388608 B
    bhalf* woutbf = (bhalf*)(ws + 39845888);     // [1024,1024] bf16  2097152 B

    bhalf* xbf  = (bhalf*)d_out;                      //  8388608 B
    bhalf* wcat = (bhalf*)((char*)d_out + 8388608);   //  6815744 B (3328x1024)

    cvt_all<<<4224, 256, 0, stream>>>(x, wqkv, w1w, w2w, w1r, w2r, wout, xbf, wcat, woutbf);
    qkv_lines_gemm128<<<dim3(32, 26), 256, 0, stream>>>(xbf, wcat, bqkv, qb, kbuf, vtb, proj);
    build_lines<<<256, 256, 0, stream>>>(proj, bsc, dlog, r8, j8);
    attn_kernel<<<1024, 256, 0, stream>>>(qb, kbuf, vtb, r8, j8, dlog, ao);
    out_gemm64x128<<<dim3(32, 16), 256, 0, stream>>>(ao, woutbf, bout, out);
}